// Round 2
// baseline (3389.737 us; speedup 1.0000x reference)
//
#include <hip/hip_runtime.h>
#include <hip/hip_bf16.h>
#include <math.h>

using bf16 = __hip_bfloat16;

// Problem dims (fixed by setup_inputs)
constexpr int Bc = 8, Tc = 1024, Dc = 1024, Hc = 8;
constexpr int NTc = 77, LTc = 768, KRc = 1024, Nc = 2125, Ec = 2048;
constexpr float NEGC = -1000000.0f;

// ---- Workspace layout ----
// fp32 region (element offsets into (float*)d_ws)
constexpr long F_NORM_XF = 0;                   // 473,088  (B*Nt*Lt)
constexpr long F_STATS1  = F_NORM_XF + 473088;  // 16,384   (8192 rows x {mean,rstd})
constexpr long F_STATS2  = F_STATS1 + 16384;    // 16,384
constexpr long F_KEYADD  = F_STATS2 + 16384;    // 17,000   (B*N)
constexpr long F_VALMUL  = F_KEYADD + 17000;    // 17,000
constexpr long F_SILU    = F_VALMUL + 17000;    // 16,384   (B*E)
constexpr long F_EO      = F_SILU + 16384;      // 16,384   (B*2D)
constexpr long F_ATT     = F_EO + 16384;        // 1,048,576 (B*H*128*128)
constexpr long F_ATTP    = F_ATT + 1048576;     // 4,194,304 (4 splits)
constexpr long F_END     = F_ATTP + 4194304;    // 5,815,504 floats = 23.3 MB
// bf16 region (element offsets into (bf16*)(ws + F_END))
constexpr long B_NORMX   = 0;                   // 8,388,608  (later reused as y)
constexpr long B_Q       = B_NORMX + 8388608;   // 8,388,608  (later reused as s)
constexpr long B_KEY     = B_Q + 8388608;       // 17,408,000 (B*N*D)
constexpr long B_V       = B_KEY + 17408000;    // 17,408,000
constexpr long B_END     = B_V + 17408000;      // 51,593,216 bf16 = 103.2 MB
constexpr size_t WS_NEED = (size_t)F_END * 4 + (size_t)B_END * 2;  // ~126.4 MB

__device__ __forceinline__ float b2f(bf16 v) { return __bfloat162float(v); }
__device__ __forceinline__ bf16 f2b(float v) { return __float2bfloat16(v); }
__device__ __forceinline__ float loadf(const float* p) { return *p; }
__device__ __forceinline__ float loadf(const bf16* p) { return __bfloat162float(*p); }
__device__ __forceinline__ void storef(float* p, float v) { *p = v; }
__device__ __forceinline__ void storef(bf16* p, float v) { *p = __float2bfloat16(v); }

__device__ __forceinline__ float2 block_sum2(float s, float s2) {
    #pragma unroll
    for (int off = 32; off > 0; off >>= 1) {
        s  += __shfl_down(s, off, 64);
        s2 += __shfl_down(s2, off, 64);
    }
    __shared__ float sh[4], sh2[4];
    int w = threadIdx.x >> 6, lane = threadIdx.x & 63;
    if (lane == 0) { sh[w] = s; sh2[w] = s2; }
    __syncthreads();
    s = sh[0] + sh[1] + sh[2] + sh[3];
    s2 = sh2[0] + sh2[1] + sh2[2] + sh2[3];
    return make_float2(s, s2);
}

// Row LayerNorm (materialized): one block (256 thr) per row
template <typename TO>
__global__ __launch_bounds__(256) void ln_rows(const float* __restrict__ in,
                                               const float* __restrict__ g,
                                               const float* __restrict__ b,
                                               TO* __restrict__ out, int C) {
    long row = blockIdx.x;
    const float* x = in + row * (long)C;
    TO* o = out + row * (long)C;
    float s = 0.f, s2 = 0.f;
    for (int c = threadIdx.x; c < C; c += 256) { float v = x[c]; s += v; s2 += v * v; }
    float2 r = block_sum2(s, s2);
    float mean = r.x / C;
    float var = r.y / C - mean * mean;
    float inv = rsqrtf(var + 1e-5f);
    for (int c = threadIdx.x; c < C; c += 256)
        storef(&o[c], (x[c] - mean) * inv * g[c] + b[c]);
}

// Stats only (mean, rstd) over motion rows of width 1024
__global__ __launch_bounds__(256) void ln_stats_rows(const float* __restrict__ in,
                                                     float* __restrict__ stats) {
    long row = blockIdx.x;  // 0..8191
    const float* x = in + row * 1024;
    float s = 0.f, s2 = 0.f;
    for (int c = threadIdx.x; c < 1024; c += 256) { float v = x[c]; s += v; s2 += v * v; }
    float2 r = block_sum2(s, s2);
    if (threadIdx.x == 0) {
        float mean = r.x / 1024.f;
        float var = r.y / 1024.f - mean * mean;
        stats[2 * row] = mean;
        stats[2 * row + 1] = rsqrtf(var + 1e-5f);
    }
}

// Stats over concat(motion_row[1024], text_row[1024]) = 2048 channels
__global__ __launch_bounds__(256) void ln_stats_cat(const float* __restrict__ motion,
                                                    const float* __restrict__ text,
                                                    float* __restrict__ stats) {
    long row = blockIdx.x;  // b*1024 + k*512 + r
    const float* m = motion + row * 1024;
    const float* tx = text + (row >> 9) * 1024;  // (row/512) = b*2+k
    float s = 0.f, s2 = 0.f;
    for (int c = threadIdx.x; c < 2048; c += 256) {
        float v = (c < 1024) ? m[c] : tx[c - 1024];
        s += v; s2 += v * v;
    }
    float2 r = block_sum2(s, s2);
    if (threadIdx.x == 0) {
        float mean = r.x / 2048.f;
        float var = r.y / 2048.f - mean * mean;
        stats[2 * row] = mean;
        stats[2 * row + 1] = rsqrtf(var + 1e-5f);
    }
}

// Per-(b, n) key additive mask and value multiplicative mask
__global__ __launch_bounds__(256) void prep_masks(const int* __restrict__ cond_type,
                                                  const float* __restrict__ src_mask,
                                                  const float* __restrict__ re_mask,
                                                  float* __restrict__ key_add,
                                                  float* __restrict__ val_mul) {
    int idx = blockIdx.x * 256 + threadIdx.x;
    if (idx >= Bc * Nc) return;
    int b = idx / Nc, n = idx % Nc;
    int ct = cond_type[b];
    float text_ct = ((ct % 10) > 0) ? 1.f : 0.f;
    float retr_ct = ((ct / 10) > 0) ? 1.f : 0.f;
    float add, mul;
    if (n < NTc) {
        add = (1.f - text_ct) * NEGC; mul = text_ct;
    } else if (n < NTc + KRc) {
        float rm = re_mask[b * KRc + (n - NTc)];
        add = (1.f - retr_ct) * NEGC + (1.f - rm) * NEGC;
        mul = retr_ct * rm;
    } else {
        float sm = src_mask[b * Tc + (n - NTc - KRc)];
        add = (1.f - sm) * NEGC; mul = sm;
    }
    key_add[idx] = add;
    val_mul[idx] = mul;
}

// Generic batched GEMM: C = (A @ W + bias + rowadd[m]) * rowmul[m] + addC
// 64x64 tile, BK=16, 256 threads, 4x4 per thread. fp32 accumulate.
template <typename TA, typename TC>
__global__ __launch_bounds__(256) void gemm_ep(
    const TA* __restrict__ A, int lda, long sA,
    const float* __restrict__ W, int ldw,
    const float* __restrict__ bias,
    const float* __restrict__ rowadd, int sRA,
    const float* __restrict__ rowmul, int sRM,
    const float* __restrict__ addC, int ldac, long sAC,
    TC* __restrict__ C, int ldc, long sC,
    int M, int N, int K) {
    int bz = blockIdx.z;
    A += (long)bz * sA;
    C += (long)bz * sC;
    if (rowadd) rowadd += (long)bz * sRA;
    if (rowmul) rowmul += (long)bz * sRM;
    if (addC) addC += (long)bz * sAC;

    const int tile_m = blockIdx.y * 64;
    const int tile_n = blockIdx.x * 64;

    __shared__ __align__(16) float As[16][68];
    __shared__ __align__(16) float Ws[16][64];

    int tid = threadIdx.x;
    int tx = tid & 15, ty = tid >> 4;
    float acc[4][4] = {};

    for (int k0 = 0; k0 < K; k0 += 16) {
        for (int e = tid; e < 1024; e += 256) {
            int m = e >> 4, k = e & 15;
            int gm = tile_m + m;
            As[k][m] = (gm < M) ? loadf(&A[(long)gm * lda + k0 + k]) : 0.f;
        }
        for (int e = tid; e < 1024; e += 256) {
            int k = e >> 6, n = e & 63;
            Ws[k][n] = W[(long)(k0 + k) * ldw + tile_n + n];
        }
        __syncthreads();
        #pragma unroll
        for (int k = 0; k < 16; ++k) {
            float4 av = *(const float4*)&As[k][ty * 4];
            float4 wv = *(const float4*)&Ws[k][tx * 4];
            float a[4] = {av.x, av.y, av.z, av.w};
            float w[4] = {wv.x, wv.y, wv.z, wv.w};
            #pragma unroll
            for (int i = 0; i < 4; ++i)
                #pragma unroll
                for (int j = 0; j < 4; ++j)
                    acc[i][j] = fmaf(a[i], w[j], acc[i][j]);
        }
        __syncthreads();
    }
    #pragma unroll
    for (int i = 0; i < 4; ++i) {
        int gm = tile_m + ty * 4 + i;
        if (gm >= M) continue;
        float ra = rowadd ? rowadd[gm] : 0.f;
        float rm = rowmul ? rowmul[gm] : 1.f;
        #pragma unroll
        for (int j = 0; j < 4; ++j) {
            int gn = tile_n + tx * 4 + j;
            float v = acc[i][j] + (bias ? bias[gn] : 0.f) + ra;
            v *= rm;
            if (addC) v += addC[(long)gm * ldac + gn];
            storef(&C[(long)gm * ldc + gn], v);
        }
    }
}

// GEMM with LayerNorm fused into A staging. A is a virtual matrix:
//   col c < 1024 -> motion[row_glob*1024 + c]
//   col c >= 1024 -> text[(row_glob>>9)*1024 + c-1024]
// normalized with stats[row_glob] and (g, bvec). M = 1024 per batch, grid.z = B.
template <typename TC>
__global__ __launch_bounds__(256) void gemm_lnA(
    const float* __restrict__ motion,
    const float* __restrict__ text,
    const float* __restrict__ stats,
    const float* __restrict__ g, const float* __restrict__ bvec,
    const float* __restrict__ W, int ldw,
    const float* __restrict__ bias,
    const float* __restrict__ rowadd, int sRA,
    const float* __restrict__ rowmul, int sRM,
    TC* __restrict__ C, int ldc, long sC,
    int K) {
    int bz = blockIdx.z;
    C += (long)bz * sC;
    if (rowadd) rowadd += (long)bz * sRA;
    if (rowmul) rowmul += (long)bz * sRM;

    const int tile_m = blockIdx.y * 64;
    const int tile_n = blockIdx.x * 64;

    __shared__ __align__(16) float As[16][68];
    __shared__ __align__(16) float Ws[16][64];

    int tid = threadIdx.x;
    int tx = tid & 15, ty = tid >> 4;
    float acc[4][4] = {};

    for (int k0 = 0; k0 < K; k0 += 16) {
        for (int e = tid; e < 1024; e += 256) {
            int m = e >> 4, k = e & 15;
            long rg = (long)bz * 1024 + tile_m + m;
            int c = k0 + k;
            float v = (c < 1024) ? motion[rg * 1024 + c]
                                 : text[(rg >> 9) * 1024 + (c - 1024)];
            As[k][m] = (v - stats[2 * rg]) * stats[2 * rg + 1] * g[c] + bvec[c];
        }
        for (int e = tid; e < 1024; e += 256) {
            int k = e >> 6, n = e & 63;
            Ws[k][n] = W[(long)(k0 + k) * ldw + tile_n + n];
        }
        __syncthreads();
        #pragma unroll
        for (int k = 0; k < 16; ++k) {
            float4 av = *(const float4*)&As[k][ty * 4];
            float4 wv = *(const float4*)&Ws[k][tx * 4];
            float a[4] = {av.x, av.y, av.z, av.w};
            float w[4] = {wv.x, wv.y, wv.z, wv.w};
            #pragma unroll
            for (int i = 0; i < 4; ++i)
                #pragma unroll
                for (int j = 0; j < 4; ++j)
                    acc[i][j] = fmaf(a[i], w[j], acc[i][j]);
        }
        __syncthreads();
    }
    #pragma unroll
    for (int i = 0; i < 4; ++i) {
        int gm = tile_m + ty * 4 + i;
        float ra = rowadd ? rowadd[gm] : 0.f;
        float rm = rowmul ? rowmul[gm] : 1.f;
        #pragma unroll
        for (int j = 0; j < 4; ++j) {
            int gn = tile_n + tx * 4 + j;
            float v = acc[i][j] + (bias ? bias[gn] : 0.f) + ra;
            v *= rm;
            storef(&C[(long)gm * ldc + gn], v);
        }
    }
}

// q softmax over head dim (128), bf16 in place. One block of 128 per (b,t,h).
__global__ __launch_bounds__(128) void softmax_head(bf16* __restrict__ q) {
    long row = blockIdx.x;
    bf16* p = q + row * 128;
    int tid = threadIdx.x;
    float v = b2f(p[tid]);
    __shared__ float red[128];
    red[tid] = v; __syncthreads();
    #pragma unroll
    for (int s = 64; s > 0; s >>= 1) {
        if (tid < s) red[tid] = fmaxf(red[tid], red[tid + s]);
        __syncthreads();
    }
    float mx = red[0];
    __syncthreads();
    float e = expf(v - mx);
    red[tid] = e; __syncthreads();
    #pragma unroll
    for (int s = 64; s > 0; s >>= 1) {
        if (tid < s) red[tid] += red[tid + s];
        __syncthreads();
    }
    p[tid] = f2b(e / red[0]);
}

// k softmax over tokens (N=2125) per column, bf16 in place.
// Block: 64 columns x 4 N-chunks. Grid: (D/64, B)
__global__ __launch_bounds__(256) void softmax_tokens(bf16* __restrict__ key) {
    int b = blockIdx.y;
    int lane = threadIdx.x & 63;
    int ch = threadIdx.x >> 6;
    int c = blockIdx.x * 64 + lane;
    bf16* kp = key + (long)b * Nc * Dc + c;
    const int per = (Nc + 3) / 4;  // 532
    int n0 = ch * per, n1 = min(Nc, n0 + per);
    float mx = -3.0e38f;
    for (int n = n0; n < n1; ++n) mx = fmaxf(mx, b2f(kp[(long)n * Dc]));
    __shared__ float redm[4][64];
    redm[ch][lane] = mx; __syncthreads();
    mx = fmaxf(fmaxf(redm[0][lane], redm[1][lane]), fmaxf(redm[2][lane], redm[3][lane]));
    float sum = 0.f;
    for (int n = n0; n < n1; ++n) sum += expf(b2f(kp[(long)n * Dc]) - mx);
    __shared__ float reds[4][64];
    reds[ch][lane] = sum; __syncthreads();
    sum = reds[0][lane] + reds[1][lane] + reds[2][lane] + reds[3][lane];
    float inv = 1.f / sum;
    for (int n = n0; n < n1; ++n) {
        long idx = (long)n * Dc;
        kp[idx] = f2b(expf(b2f(kp[idx]) - mx) * inv);
    }
}

// att_part[split][bh][d][l] = sum_{n in split} k[b,n,h*128+d] * v[b,n,h*128+l]
constexpr int ATT_SPLIT = 4;
__global__ __launch_bounds__(256) void att_kernel(const bf16* __restrict__ key,
                                                  const bf16* __restrict__ v,
                                                  float* __restrict__ att_part) {
    int bh = blockIdx.x;
    int b = bh >> 3, h = bh & 7;
    int split = blockIdx.y;
    const bf16* kb = key + (long)b * Nc * Dc + h * 128;
    const bf16* vb = v + (long)b * Nc * Dc + h * 128;
    float* ap = att_part + ((long)split * 64 + bh) * 16384;
    const int per = (Nc + ATT_SPLIT - 1) / ATT_SPLIT;  // 532
    int n0 = split * per, n1 = min(Nc, n0 + per);
    __shared__ float ks[16][128], vs[16][128];
    int tid = threadIdx.x, tx = tid & 15, ty = tid >> 4;
    float acc[8][8] = {};
    for (int nb = n0; nb < n1; nb += 16) {
        int nc = min(16, n1 - nb);
        for (int e = tid; e < 2048; e += 256) {
            int nn = e >> 7, d = e & 127;
            float kvv = 0.f, vvv = 0.f;
            if (nn < nc) {
                long off = (long)(nb + nn) * Dc + d;
                kvv = b2f(kb[off]); vvv = b2f(vb[off]);
            }
            ks[nn][d] = kvv; vs[nn][d] = vvv;
        }
        __syncthreads();
        #pragma unroll
        for (int nn = 0; nn < 16; ++nn) {
            float kr[8], vr[8];
            #pragma unroll
            for (int i = 0; i < 8; ++i) kr[i] = ks[nn][ty * 8 + i];
            #pragma unroll
            for (int j = 0; j < 8; ++j) vr[j] = vs[nn][tx * 8 + j];
            #pragma unroll
            for (int i = 0; i < 8; ++i)
                #pragma unroll
                for (int j = 0; j < 8; ++j)
                    acc[i][j] = fmaf(kr[i], vr[j], acc[i][j]);
        }
        __syncthreads();
    }
    for (int i = 0; i < 8; ++i)
        for (int j = 0; j < 8; ++j)
            ap[(ty * 8 + i) * 128 + tx * 8 + j] = acc[i][j];
}

__global__ __launch_bounds__(256) void reduce_att(const float* __restrict__ att_part,
                                                  float* __restrict__ att) {
    long idx = (long)blockIdx.x * 256 + threadIdx.x;
    if (idx >= (long)64 * 16384) return;
    float s = 0.f;
    #pragma unroll
    for (int sp = 0; sp < ATT_SPLIT; ++sp) s += att_part[(long)sp * 64 * 16384 + idx];
    att[idx] = s;
}

// y[b,t,h*128+l] = sum_d q[b,t,h*128+d] * att[bh][d][l]
__global__ __launch_bounds__(256) void y_kernel(const bf16* __restrict__ q,
                                                const float* __restrict__ att,
                                                bf16* __restrict__ y) {
    int bh = blockIdx.y;
    int b = bh >> 3, h = bh & 7;
    const bf16* qb = q + (long)b * Tc * Dc + h * 128;
    const float* ab = att + (long)bh * 16384;
    bf16* yb = y + (long)b * Tc * Dc + h * 128;
    int t0 = blockIdx.x * 64;
    __shared__ float qs[16][68];
    __shared__ float as[16][128];
    int tid = threadIdx.x, tx = tid & 15, ty = tid >> 4;
    float acc[4][8] = {};
    for (int k0 = 0; k0 < 128; k0 += 16) {
        for (int e = tid; e < 1024; e += 256) {
            int m = e >> 4, k = e & 15;
            qs[k][m] = b2f(qb[(long)(t0 + m) * Dc + k0 + k]);
        }
        for (int e = tid; e < 2048; e += 256) {
            int k = e >> 7, n = e & 127;
            as[k][n] = ab[(k0 + k) * 128 + n];
        }
        __syncthreads();
        #pragma unroll
        for (int k = 0; k < 16; ++k) {
            float a[4], w[8];
            #pragma unroll
            for (int i = 0; i < 4; ++i) a[i] = qs[k][ty * 4 + i];
            #pragma unroll
            for (int j = 0; j < 8; ++j) w[j] = as[k][tx * 8 + j];
            #pragma unroll
            for (int i = 0; i < 4; ++i)
                #pragma unroll
                for (int j = 0; j < 8; ++j)
                    acc[i][j] = fmaf(a[i], w[j], acc[i][j]);
        }
        __syncthreads();
    }
    for (int i = 0; i < 4; ++i)
        for (int j = 0; j < 8; ++j)
            yb[(long)(t0 + ty * 4 + i) * Dc + tx * 8 + j] = f2b(acc[i][j]);
}

__global__ __launch_bounds__(256) void silu_kernel(const float* __restrict__ in,
                                                   float* __restrict__ out, int n) {
    int i = blockIdx.x * 256 + threadIdx.x;
    if (i < n) { float v = in[i]; out[i] = v / (1.f + expf(-v)); }
}

// s = silu( LN(y)*(1+scale) + shift ). One block per (b,t) row. bf16 in/out.
__global__ __launch_bounds__(256) void film_kernel(const bf16* __restrict__ y,
                                                   const float* __restrict__ eo,
                                                   const float* __restrict__ g,
                                                   const float* __restrict__ bta,
                                                   bf16* __restrict__ s) {
    long row = blockIdx.x;
    int b = (int)(row >> 10);
    const bf16* yr = y + row * Dc;
    float sum = 0.f, sum2 = 0.f;
    for (int c = threadIdx.x; c < Dc; c += 256) { float v = b2f(yr[c]); sum += v; sum2 += v * v; }
    float2 r = block_sum2(sum, sum2);
    float mean = r.x / Dc;
    float var = r.y / Dc - mean * mean;
    float inv = rsqrtf(var + 1e-5f);
    const float* sc = eo + (long)b * 2048;
    const float* sf = sc + 1024;
    bf16* so = s + row * Dc;
    for (int c = threadIdx.x; c < Dc; c += 256) {
        float v = (b2f(yr[c]) - mean) * inv * g[c] + bta[c];
        v = v * (1.f + sc[c]) + sf[c];
        so[c] = f2b(v / (1.f + expf(-v)));
    }
}

extern "C" void kernel_launch(void* const* d_in, const int* in_sizes, int n_in,
                              void* d_out, int out_size, void* d_ws, size_t ws_size,
                              hipStream_t stream) {
    if (ws_size < WS_NEED) return;  // diagnostic bail: shows as absmax fail, not a crash

    const float* x         = (const float*)d_in[0];
    const float* xf        = (const float*)d_in[1];
    const float* emb       = (const float*)d_in[2];
    const float* src_mask  = (const float*)d_in[3];
    const int*   cond_type = (const int*)d_in[4];
    const float* re_motion = (const float*)d_in[5];
    const float* re_text   = (const float*)d_in[6];
    const float* re_mask   = (const float*)d_in[7];
    const float* ln_g  = (const float*)d_in[8];
    const float* ln_b  = (const float*)d_in[9];
    const float* tln_g = (const float*)d_in[10];
    const float* tln_b = (const float*)d_in[11];
    const float* rn1_g = (const float*)d_in[12];
    const float* rn1_b = (const float*)d_in[13];
    const float* rn2_g = (const float*)d_in[14];
    const float* rn2_b = (const float*)d_in[15];
    const float* Wq  = (const float*)d_in[16];
    const float* bq  = (const float*)d_in[17];
    const float* Wkt = (const float*)d_in[18];
    const float* bkt = (const float*)d_in[19];
    const float* Wvt = (const float*)d_in[20];
    const float* bvt = (const float*)d_in[21];
    const float* Wkm = (const float*)d_in[22];
    const float* bkm = (const float*)d_in[23];
    const float* Wvm = (const float*)d_in[24];
    const float* bvm = (const float*)d_in[25];
    const float* Wkr = (const float*)d_in[26];
    const float* bkr = (const float*)d_in[27];
    const float* Wvr = (const float*)d_in[28];
    const float* bvr = (const float*)d_in[29];
    const float* We  = (const float*)d_in[30];
    const float* be  = (const float*)d_in[31];
    const float* sln_g = (const float*)d_in[32];
    const float* sln_b = (const float*)d_in[33];
    const float* Wo  = (const float*)d_in[34];
    const float* bo  = (const float*)d_in[35];

    float* ws = (float*)d_ws;
    float* norm_xf  = ws + F_NORM_XF;
    float* stats1   = ws + F_STATS1;
    float* stats2   = ws + F_STATS2;
    float* key_add  = ws + F_KEYADD;
    float* val_mul  = ws + F_VALMUL;
    float* silu_emb = ws + F_SILU;
    float* eo       = ws + F_EO;
    float* att      = ws + F_ATT;
    float* att_part = ws + F_ATTP;
    bf16* wb = (bf16*)(ws + F_END);
    bf16* norm_x16 = wb + B_NORMX;
    bf16* q16      = wb + B_Q;
    bf16* key16    = wb + B_KEY;
    bf16* v16      = wb + B_V;
    bf16* y16 = norm_x16;  // norm_x dead after value_motion GEMM
    bf16* s16 = q16;       // q dead after y_kernel

    float* out = (float*)d_out;
    const long sKey = (long)Nc * Dc;  // 2,176,000

    // 1. LayerNorms + stats
    ln_rows<bf16><<<dim3(Bc * Tc), dim3(256), 0, stream>>>(x, ln_g, ln_b, norm_x16, Dc);
    ln_rows<float><<<dim3(Bc * NTc), dim3(256), 0, stream>>>(xf, tln_g, tln_b, norm_xf, LTc);
    ln_stats_cat<<<dim3(Bc * KRc), dim3(256), 0, stream>>>(re_motion, re_text, stats1);
    ln_stats_rows<<<dim3(Bc * KRc), dim3(256), 0, stream>>>(re_motion, stats2);

    // 2. Masks
    prep_masks<<<dim3((Bc * Nc + 255) / 256), dim3(256), 0, stream>>>(
        cond_type, src_mask, re_mask, key_add, val_mul);

    // 3. GEMMs
    // query = norm_x @ Wq + bq  (flat M=8192)
    gemm_ep<bf16, bf16><<<dim3(16, 128, 1), dim3(256), 0, stream>>>(
        norm_x16, Dc, 0, Wq, Dc, bq, nullptr, 0, nullptr, 0, nullptr, 0, 0,
        q16, Dc, 0, Bc * Tc, Dc, Dc);
    // key_text
    gemm_ep<float, bf16><<<dim3(16, 2, Bc), dim3(256), 0, stream>>>(
        norm_xf, LTc, (long)NTc * LTc, Wkt, Dc, bkt, key_add + 0, Nc, nullptr, 0,
        nullptr, 0, 0, key16 + 0, Dc, sKey, NTc, Dc, LTc);
    // key_retr (LN fused)
    gemm_lnA<bf16><<<dim3(16, 16, Bc), dim3(256), 0, stream>>>(
        re_motion, re_text, stats1, rn1_g, rn1_b, Wkr, Dc, bkr,
        key_add + NTc, Nc, nullptr, 0, key16 + (long)NTc * Dc, Dc, sKey, 2048);
    // key_motion
    gemm_ep<bf16, bf16><<<dim3(16, 16, Bc), dim3(256), 0, stream>>>(
        norm_x16, Dc, (long)Tc * Dc, Wkm, Dc, bkm, key_add + NTc + KRc, Nc, nullptr, 0,
        nullptr, 0, 0, key16 + (long)(NTc + KRc) * Dc, Dc, sKey, Tc, Dc, Dc);
    // value_text
    gemm_ep<float, bf16><<<dim3(16, 2, Bc), dim3(256), 0, stream>>>(
        norm_xf, LTc, (long)NTc * LTc, Wvt, Dc, bvt, nullptr, 0, val_mul + 0, Nc,
        nullptr, 0, 0, v16 + 0, Dc, sKey, NTc, Dc, LTc);
    // value_retr (LN fused)
    gemm_lnA<bf16><<<dim3(16, 16, Bc), dim3(256), 0, stream>>>(
        re_motion, nullptr, stats2, rn2_g, rn2_b, Wvr, Dc, bvr,
        nullptr, 0, val_mul + NTc, Nc, v16 + (long)NTc * Dc, Dc, sKey, 1024);
    // value_motion
    gemm_ep<bf16, bf16><<<dim3(16, 16, Bc), dim3(256), 0, stream>>>(
        norm_x16, Dc, (long)Tc * Dc, Wvm, Dc, bvm, nullptr, 0, val_mul + NTc + KRc, Nc,
        nullptr, 0, 0, v16 + (long)(NTc + KRc) * Dc, Dc, sKey, Tc, Dc, Dc);

    // 4. Softmaxes
    softmax_head<<<dim3(Bc * Tc * Hc), dim3(128), 0, stream>>>(q16);
    softmax_tokens<<<dim3(Dc / 64, Bc), dim3(256), 0, stream>>>(key16);

    // 5. att = k^T v (split over N, then reduce)
    att_kernel<<<dim3(Bc * Hc, ATT_SPLIT), dim3(256), 0, stream>>>(key16, v16, att_part);
    reduce_att<<<dim3((64 * 16384 + 255) / 256), dim3(256), 0, stream>>>(att_part, att);

    // 6. y = q @ att  (y overlays norm_x region)
    y_kernel<<<dim3(Tc / 64, Bc * Hc), dim3(256), 0, stream>>>(q16, att, y16);

    // 7. Time-embedding FiLM params
    silu_kernel<<<dim3((Bc * Ec + 255) / 256), dim3(256), 0, stream>>>(emb, silu_emb, Bc * Ec);
    gemm_ep<float, float><<<dim3(32, 1, 1), dim3(256), 0, stream>>>(
        silu_emb, Ec, 0, We, 2048, be, nullptr, 0, nullptr, 0, nullptr, 0, 0,
        eo, 2048, 0, Bc, 2048, Ec);

    // 8. FiLM + silu  (s overlays q region)
    film_kernel<<<dim3(Bc * Tc), dim3(256), 0, stream>>>(y16, eo, sln_g, sln_b, s16);

    // 9. out = x + s @ Wo + bo
    gemm_ep<bf16, float><<<dim3(16, 128, 1), dim3(256), 0, stream>>>(
        s16, Dc, 0, Wo, Dc, bo, nullptr, 0, nullptr, 0, x, Dc, 0,
        out, Dc, 0, Bc * Tc, Dc, Dc);
}

// Round 3
// 1850.956 us; speedup vs baseline: 1.8313x; 1.8313x over previous
//
#include <hip/hip_runtime.h>
#include <hip/hip_bf16.h>
#include <math.h>

using bf16 = __hip_bfloat16;

typedef short s16x8 __attribute__((ext_vector_type(8)));
typedef float f32x4 __attribute__((ext_vector_type(4)));

// Problem dims (fixed by setup_inputs)
constexpr int Bc = 8, Tc = 1024, Dc = 1024, Hc = 8;
constexpr int NTc = 77, LTc = 768, KRc = 1024, Nc = 2125, Ec = 2048;
constexpr float NEGC = -1000000.0f;

// ---- Workspace layout ----
// fp32 region (element offsets into (float*)d_ws)
constexpr long F_STATS1 = 0;                    // 16,384 (8192 rows x {mean,rstd})
constexpr long F_STATS2 = F_STATS1 + 16384;     // 16,384
constexpr long F_KEYADD = F_STATS2 + 16384;     // 17,000 (B*N)
constexpr long F_VALMUL = F_KEYADD + 17000;     // 17,000
constexpr long F_SILU   = F_VALMUL + 17000;     // 16,384 (B*E)
constexpr long F_EO     = F_SILU + 16384;       // 16,384 (B*2D)
constexpr long F_ATT    = F_EO + 16384;         // 1,048,576 (B*H*128*128)
constexpr long F_END    = F_ATT + 1048576;      // 1,148,112 floats
// bf16 region (element offsets into (bf16*)(ws + F_END))
constexpr long B_NORMX = 0;                     // 8,388,608 (reused: att_part fp32, then y16)
constexpr long B_Q     = B_NORMX + 8388608;     // 8,388,608 (reused: s16)
constexpr long B_KEY   = B_Q + 8388608;         // 17,408,000
constexpr long B_V     = B_KEY + 17408000;      // 17,408,000
constexpr long B_NXF   = B_V + 17408000;        // 473,088 (B*Nt*Lt)
constexpr long B_WQ    = B_NXF + 473088;        // 1,048,576
constexpr long B_WKT   = B_WQ + 1048576;        // 786,432 [1024][768]
constexpr long B_WVT   = B_WKT + 786432;        // 786,432
constexpr long B_WKM   = B_WVT + 786432;        // 1,048,576
constexpr long B_WVM   = B_WKM + 1048576;       // 1,048,576
constexpr long B_WKR   = B_WVM + 1048576;       // 2,097,152 [1024][2048]
constexpr long B_WVR   = B_WKR + 2097152;       // 1,048,576
constexpr long B_WO    = B_WVR + 1048576;       // 1,048,576
constexpr long B_END   = B_WO + 1048576;        // 60,979,200 bf16
constexpr size_t WS_NEED = (size_t)F_END * 4 + (size_t)B_END * 2;  // ~126.6 MB

__device__ __forceinline__ float b2f(bf16 v) { return __bfloat162float(v); }
__device__ __forceinline__ bf16 f2b(float v) { return __float2bfloat16(v); }
__device__ __forceinline__ short f2s(float v) {
    bf16 h = __float2bfloat16(v);
    return *reinterpret_cast<short*>(&h);
}
__device__ __forceinline__ float loadf(const float* p) { return *p; }
__device__ __forceinline__ float loadf(const bf16* p) { return __bfloat162float(*p); }
__device__ __forceinline__ void storef(float* p, float v) { *p = v; }
__device__ __forceinline__ void storef(bf16* p, float v) { *p = __float2bfloat16(v); }

__device__ __forceinline__ float2 block_sum2(float s, float s2) {
    #pragma unroll
    for (int off = 32; off > 0; off >>= 1) {
        s  += __shfl_down(s, off, 64);
        s2 += __shfl_down(s2, off, 64);
    }
    __shared__ float sh[4], sh2[4];
    int w = threadIdx.x >> 6, lane = threadIdx.x & 63;
    if (lane == 0) { sh[w] = s; sh2[w] = s2; }
    __syncthreads();
    s = sh[0] + sh[1] + sh[2] + sh[3];
    s2 = sh2[0] + sh2[1] + sh2[2] + sh2[3];
    return make_float2(s, s2);
}

// Row LayerNorm: one block (256 thr) per row
template <typename TO>
__global__ __launch_bounds__(256) void ln_rows(const float* __restrict__ in,
                                               const float* __restrict__ g,
                                               const float* __restrict__ b,
                                               TO* __restrict__ out, int C) {
    long row = blockIdx.x;
    const float* x = in + row * (long)C;
    TO* o = out + row * (long)C;
    float s = 0.f, s2 = 0.f;
    for (int c = threadIdx.x; c < C; c += 256) { float v = x[c]; s += v; s2 += v * v; }
    float2 r = block_sum2(s, s2);
    float mean = r.x / C;
    float var = r.y / C - mean * mean;
    float inv = rsqrtf(var + 1e-5f);
    for (int c = threadIdx.x; c < C; c += 256)
        storef(&o[c], (x[c] - mean) * inv * g[c] + b[c]);
}

// Stats (mean, rstd) over rows of width 1024
__global__ __launch_bounds__(256) void ln_stats_rows(const float* __restrict__ in,
                                                     float* __restrict__ stats) {
    long row = blockIdx.x;
    const float* x = in + row * 1024;
    float s = 0.f, s2 = 0.f;
    for (int c = threadIdx.x; c < 1024; c += 256) { float v = x[c]; s += v; s2 += v * v; }
    float2 r = block_sum2(s, s2);
    if (threadIdx.x == 0) {
        float mean = r.x / 1024.f;
        float var = r.y / 1024.f - mean * mean;
        stats[2 * row] = mean;
        stats[2 * row + 1] = rsqrtf(var + 1e-5f);
    }
}

// Stats over concat(motion_row[1024], text_row[1024])
__global__ __launch_bounds__(256) void ln_stats_cat(const float* __restrict__ motion,
                                                    const float* __restrict__ text,
                                                    float* __restrict__ stats) {
    long row = blockIdx.x;  // b*1024 + k*512 + r
    const float* m = motion + row * 1024;
    const float* tx = text + (row >> 9) * 1024;
    float s = 0.f, s2 = 0.f;
    for (int c = threadIdx.x; c < 2048; c += 256) {
        float v = (c < 1024) ? m[c] : tx[c - 1024];
        s += v; s2 += v * v;
    }
    float2 r = block_sum2(s, s2);
    if (threadIdx.x == 0) {
        float mean = r.x / 2048.f;
        float var = r.y / 2048.f - mean * mean;
        stats[2 * row] = mean;
        stats[2 * row + 1] = rsqrtf(var + 1e-5f);
    }
}

// Per-(b, n) key additive mask and value multiplicative mask
__global__ __launch_bounds__(256) void prep_masks(const int* __restrict__ cond_type,
                                                  const float* __restrict__ src_mask,
                                                  const float* __restrict__ re_mask,
                                                  float* __restrict__ key_add,
                                                  float* __restrict__ val_mul) {
    int idx = blockIdx.x * 256 + threadIdx.x;
    if (idx >= Bc * Nc) return;
    int b = idx / Nc, n = idx % Nc;
    int ct = cond_type[b];
    float text_ct = ((ct % 10) > 0) ? 1.f : 0.f;
    float retr_ct = ((ct / 10) > 0) ? 1.f : 0.f;
    float add, mul;
    if (n < NTc) {
        add = (1.f - text_ct) * NEGC; mul = text_ct;
    } else if (n < NTc + KRc) {
        float rm = re_mask[b * KRc + (n - NTc)];
        add = (1.f - retr_ct) * NEGC + (1.f - rm) * NEGC;
        mul = retr_ct * rm;
    } else {
        float sm = src_mask[b * Tc + (n - NTc - KRc)];
        add = (1.f - sm) * NEGC; mul = sm;
    }
    key_add[idx] = add;
    val_mul[idx] = mul;
}

// Transpose + convert weight: W[K][N] fp32 -> Wt[N][K] bf16(short)
__global__ __launch_bounds__(256) void transpose_w(const float* __restrict__ W,
                                                   short* __restrict__ Wt,
                                                   int K, int N) {
    __shared__ float t[32][33];
    int n0 = blockIdx.x * 32, k0 = blockIdx.y * 32;
    int tx = threadIdx.x & 31, ty = threadIdx.x >> 5;  // 32 x 8
    #pragma unroll
    for (int i = 0; i < 4; ++i)
        t[ty + i * 8][tx] = W[(long)(k0 + ty + i * 8) * N + n0 + tx];
    __syncthreads();
    #pragma unroll
    for (int i = 0; i < 4; ++i)
        Wt[(long)(n0 + ty + i * 8) * K + k0 + tx] = f2s(t[tx][ty + i * 8]);
}

// ======================= MFMA GEMM (B^T layout) =========================
// C = (A @ W + bias + rowadd[m]) * rowmul[m] + addC,  W given as Bt[N][K] bf16.
// 128x128 tile, BK=64, 256 thr = 4 waves (2x2 of 64x64), 16x16x32 bf16 MFMA.
constexpr int LDST = 72;  // LDS row stride (bf16 elems): 144 B, 16B-aligned, stride 4 banks

template <typename TC>
__global__ __launch_bounds__(256) void gemm_bt(
    const short* __restrict__ A, int lda, long sA,
    const short* __restrict__ Bt, int ldb,
    const float* __restrict__ bias,
    const float* __restrict__ rowadd, int sRA,
    const float* __restrict__ rowmul, int sRM,
    const float* __restrict__ addC, int ldac, long sAC,
    TC* __restrict__ C, int ldc, long sC,
    int M, int K) {
    int bz = blockIdx.z;
    A += (long)bz * sA;
    C += (long)bz * sC;
    if (rowadd) rowadd += (long)bz * sRA;
    if (rowmul) rowmul += (long)bz * sRM;
    if (addC) addC += (long)bz * sAC;

    const int tm = blockIdx.y * 128;
    const int tn = blockIdx.x * 128;

    __shared__ __align__(16) short As[128 * LDST];
    __shared__ __align__(16) short Bs[128 * LDST];

    int tid = threadIdx.x;
    int lane = tid & 63, wid = tid >> 6;
    int wi = wid >> 1, wj = wid & 1;
    int l16 = lane & 15, quad = lane >> 4;

    f32x4 acc[4][4];
    #pragma unroll
    for (int i = 0; i < 4; ++i)
        #pragma unroll
        for (int j = 0; j < 4; ++j)
            acc[i][j] = (f32x4){0.f, 0.f, 0.f, 0.f};

    uint4 pa[4], pb[4];

    auto loadG = [&](int k0) {
        #pragma unroll
        for (int p = 0; p < 4; ++p) {
            int e = p * 256 + tid;
            int row = e >> 3, c8 = e & 7;
            int gm = tm + row;
            uint4 va = {0, 0, 0, 0};
            if (gm < M) va = *(const uint4*)(A + (long)gm * lda + k0 + c8 * 8);
            pa[p] = va;
            pb[p] = *(const uint4*)(Bt + (long)(tn + row) * ldb + k0 + c8 * 8);
        }
    };
    auto storeLDS = [&]() {
        #pragma unroll
        for (int p = 0; p < 4; ++p) {
            int e = p * 256 + tid;
            int row = e >> 3, c8 = e & 7;
            *(uint4*)&As[row * LDST + c8 * 8] = pa[p];
            *(uint4*)&Bs[row * LDST + c8 * 8] = pb[p];
        }
    };

    loadG(0);
    storeLDS();
    __syncthreads();

    int kt = 0;
    while (true) {
        int nxt = kt + 64;
        bool more = nxt < K;
        if (more) loadG(nxt);
        #pragma unroll
        for (int kk = 0; kk < 2; ++kk) {
            s16x8 af[4], bfr[4];
            #pragma unroll
            for (int i = 0; i < 4; ++i)
                af[i] = *(const s16x8*)&As[(wi * 64 + i * 16 + l16) * LDST + kk * 32 + quad * 8];
            #pragma unroll
            for (int j = 0; j < 4; ++j)
                bfr[j] = *(const s16x8*)&Bs[(wj * 64 + j * 16 + l16) * LDST + kk * 32 + quad * 8];
            #pragma unroll
            for (int i = 0; i < 4; ++i)
                #pragma unroll
                for (int j = 0; j < 4; ++j)
                    acc[i][j] = __builtin_amdgcn_mfma_f32_16x16x32_bf16(af[i], bfr[j], acc[i][j], 0, 0, 0);
        }
        if (!more) break;
        __syncthreads();
        storeLDS();
        __syncthreads();
        kt = nxt;
    }

    #pragma unroll
    for (int i = 0; i < 4; ++i) {
        #pragma unroll
        for (int r = 0; r < 4; ++r) {
            int gm = tm + wi * 64 + i * 16 + quad * 4 + r;
            if (gm >= M) continue;
            float ra = rowadd ? rowadd[gm] : 0.f;
            float rm = rowmul ? rowmul[gm] : 1.f;
            #pragma unroll
            for (int j = 0; j < 4; ++j) {
                int gn = tn + wj * 64 + j * 16 + l16;
                float v = acc[i][j][r] + (bias ? bias[gn] : 0.f) + ra;
                v *= rm;
                if (addC) v += addC[(long)gm * ldac + gn];
                storef(&C[(long)gm * ldc + gn], v);
            }
        }
    }
}

// MFMA GEMM with LayerNorm fused into A staging from fp32 sources.
// A virtual row rg = bz*1024 + tm + m; col c<1024 -> motion[rg*1024+c],
// c>=1024 -> text[(rg>>9)*1024 + c-1024]; normalized by stats[rg], g, bvec.
template <typename TC>
__global__ __launch_bounds__(256) void gemm_lnA_mfma(
    const float* __restrict__ motion, const float* __restrict__ text,
    const float* __restrict__ stats,
    const float* __restrict__ g, const float* __restrict__ bvec,
    const short* __restrict__ Bt, int ldb,
    const float* __restrict__ bias,
    const float* __restrict__ rowadd, int sRA,
    const float* __restrict__ rowmul, int sRM,
    TC* __restrict__ C, int ldc, long sC,
    int K) {
    int bz = blockIdx.z;
    C += (long)bz * sC;
    if (rowadd) rowadd += (long)bz * sRA;
    if (rowmul) rowmul += (long)bz * sRM;

    const int tm = blockIdx.y * 128;
    const int tn = blockIdx.x * 128;

    __shared__ __align__(16) short As[128 * LDST];
    __shared__ __align__(16) short Bs[128 * LDST];

    int tid = threadIdx.x;
    int lane = tid & 63, wid = tid >> 6;
    int wi = wid >> 1, wj = wid & 1;
    int l16 = lane & 15, quad = lane >> 4;

    f32x4 acc[4][4];
    #pragma unroll
    for (int i = 0; i < 4; ++i)
        #pragma unroll
        for (int j = 0; j < 4; ++j)
            acc[i][j] = (f32x4){0.f, 0.f, 0.f, 0.f};

    uint4 pa[4], pb[4];

    auto loadG = [&](int k0) {
        #pragma unroll
        for (int p = 0; p < 4; ++p) {
            int e = p * 256 + tid;
            int row = e >> 3, c8 = e & 7;
            long rg = (long)bz * 1024 + tm + row;
            int c = k0 + c8 * 8;
            const float* src = (c < 1024) ? motion + rg * 1024 + c
                                          : text + (rg >> 9) * 1024 + (c - 1024);
            float4 v0 = *(const float4*)src;
            float4 v1 = *(const float4*)(src + 4);
            float mean = stats[2 * rg], rstd = stats[2 * rg + 1];
            float4 g0 = *(const float4*)&g[c], g1 = *(const float4*)&g[c + 4];
            float4 b0 = *(const float4*)&bvec[c], b1 = *(const float4*)&bvec[c + 4];
            union { short s[8]; uint4 u; } pk;
            pk.s[0] = f2s((v0.x - mean) * rstd * g0.x + b0.x);
            pk.s[1] = f2s((v0.y - mean) * rstd * g0.y + b0.y);
            pk.s[2] = f2s((v0.z - mean) * rstd * g0.z + b0.z);
            pk.s[3] = f2s((v0.w - mean) * rstd * g0.w + b0.w);
            pk.s[4] = f2s((v1.x - mean) * rstd * g1.x + b1.x);
            pk.s[5] = f2s((v1.y - mean) * rstd * g1.y + b1.y);
            pk.s[6] = f2s((v1.z - mean) * rstd * g1.z + b1.z);
            pk.s[7] = f2s((v1.w - mean) * rstd * g1.w + b1.w);
            pa[p] = pk.u;
            pb[p] = *(const uint4*)(Bt + (long)(tn + row) * ldb + k0 + c8 * 8);
        }
    };
    auto storeLDS = [&]() {
        #pragma unroll
        for (int p = 0; p < 4; ++p) {
            int e = p * 256 + tid;
            int row = e >> 3, c8 = e & 7;
            *(uint4*)&As[row * LDST + c8 * 8] = pa[p];
            *(uint4*)&Bs[row * LDST + c8 * 8] = pb[p];
        }
    };

    loadG(0);
    storeLDS();
    __syncthreads();

    int kt = 0;
    while (true) {
        int nxt = kt + 64;
        bool more = nxt < K;
        if (more) loadG(nxt);
        #pragma unroll
        for (int kk = 0; kk < 2; ++kk) {
            s16x8 af[4], bfr[4];
            #pragma unroll
            for (int i = 0; i < 4; ++i)
                af[i] = *(const s16x8*)&As[(wi * 64 + i * 16 + l16) * LDST + kk * 32 + quad * 8];
            #pragma unroll
            for (int j = 0; j < 4; ++j)
                bfr[j] = *(const s16x8*)&Bs[(wj * 64 + j * 16 + l16) * LDST + kk * 32 + quad * 8];
            #pragma unroll
            for (int i = 0; i < 4; ++i)
                #pragma unroll
                for (int j = 0; j < 4; ++j)
                    acc[i][j] = __builtin_amdgcn_mfma_f32_16x16x32_bf16(af[i], bfr[j], acc[i][j], 0, 0, 0);
        }
        if (!more) break;
        __syncthreads();
        storeLDS();
        __syncthreads();
        kt = nxt;
    }

    #pragma unroll
    for (int i = 0; i < 4; ++i) {
        #pragma unroll
        for (int r = 0; r < 4; ++r) {
            int gm = tm + wi * 64 + i * 16 + quad * 4 + r;
            float ra = rowadd ? rowadd[gm] : 0.f;
            float rm = rowmul ? rowmul[gm] : 1.f;
            #pragma unroll
            for (int j = 0; j < 4; ++j) {
                int gn = tn + wj * 64 + j * 16 + l16;
                float v = acc[i][j][r] + (bias ? bias[gn] : 0.f) + ra;
                v *= rm;
                storef(&C[(long)gm * ldc + gn], v);
            }
        }
    }
}

// Small fp32 GEMM for eo (M=8): C = A @ W + bias
__global__ __launch_bounds__(256) void gemm_ep(
    const float* __restrict__ A, int lda,
    const float* __restrict__ W, int ldw,
    const float* __restrict__ bias,
    float* __restrict__ C, int ldc,
    int M, int K) {
    const int tile_m = blockIdx.y * 64;
    const int tile_n = blockIdx.x * 64;
    __shared__ __align__(16) float As[16][68];
    __shared__ __align__(16) float Ws[16][64];
    int tid = threadIdx.x;
    int tx = tid & 15, ty = tid >> 4;
    float acc[4][4] = {};
    for (int k0 = 0; k0 < K; k0 += 16) {
        for (int e = tid; e < 1024; e += 256) {
            int m = e >> 4, k = e & 15;
            int gm = tile_m + m;
            As[k][m] = (gm < M) ? A[(long)gm * lda + k0 + k] : 0.f;
        }
        for (int e = tid; e < 1024; e += 256) {
            int k = e >> 6, n = e & 63;
            Ws[k][n] = W[(long)(k0 + k) * ldw + tile_n + n];
        }
        __syncthreads();
        #pragma unroll
        for (int k = 0; k < 16; ++k) {
            float4 av = *(const float4*)&As[k][ty * 4];
            float4 wv = *(const float4*)&Ws[k][tx * 4];
            float a[4] = {av.x, av.y, av.z, av.w};
            float w[4] = {wv.x, wv.y, wv.z, wv.w};
            #pragma unroll
            for (int i = 0; i < 4; ++i)
                #pragma unroll
                for (int j = 0; j < 4; ++j)
                    acc[i][j] = fmaf(a[i], w[j], acc[i][j]);
        }
        __syncthreads();
    }
    #pragma unroll
    for (int i = 0; i < 4; ++i) {
        int gm = tile_m + ty * 4 + i;
        if (gm >= M) continue;
        #pragma unroll
        for (int j = 0; j < 4; ++j) {
            int gn = tile_n + tx * 4 + j;
            C[(long)gm * ldc + gn] = acc[i][j] + (bias ? bias[gn] : 0.f);
        }
    }
}

// q softmax over head dim (128), bf16 in place.
__global__ __launch_bounds__(128) void softmax_head(bf16* __restrict__ q) {
    long row = blockIdx.x;
    bf16* p = q + row * 128;
    int tid = threadIdx.x;
    float v = b2f(p[tid]);
    __shared__ float red[128];
    red[tid] = v; __syncthreads();
    #pragma unroll
    for (int s = 64; s > 0; s >>= 1) {
        if (tid < s) red[tid] = fmaxf(red[tid], red[tid + s]);
        __syncthreads();
    }
    float mx = red[0];
    __syncthreads();
    float e = expf(v - mx);
    red[tid] = e; __syncthreads();
    #pragma unroll
    for (int s = 64; s > 0; s >>= 1) {
        if (tid < s) red[tid] += red[tid + s];
        __syncthreads();
    }
    p[tid] = f2b(e / red[0]);
}

// k softmax over tokens (N=2125) per column, bf16 in place.
__global__ __launch_bounds__(256) void softmax_tokens(bf16* __restrict__ key) {
    int b = blockIdx.y;
    int lane = threadIdx.x & 63;
    int ch = threadIdx.x >> 6;
    int c = blockIdx.x * 64 + lane;
    bf16* kp = key + (long)b * Nc * Dc + c;
    const int per = (Nc + 3) / 4;  // 532
    int n0 = ch * per, n1 = min(Nc, n0 + per);
    float mx = -3.0e38f;
    for (int n = n0; n < n1; ++n) mx = fmaxf(mx, b2f(kp[(long)n * Dc]));
    __shared__ float redm[4][64];
    redm[ch][lane] = mx; __syncthreads();
    mx = fmaxf(fmaxf(redm[0][lane], redm[1][lane]), fmaxf(redm[2][lane], redm[3][lane]));
    float sum = 0.f;
    for (int n = n0; n < n1; ++n) sum += expf(b2f(kp[(long)n * Dc]) - mx);
    __shared__ float reds[4][64];
    reds[ch][lane] = sum; __syncthreads();
    sum = reds[0][lane] + reds[1][lane] + reds[2][lane] + reds[3][lane];
    float inv = 1.f / sum;
    for (int n = n0; n < n1; ++n) {
        long idx = (long)n * Dc;
        kp[idx] = f2b(expf(b2f(kp[idx]) - mx) * inv);
    }
}

// att_part[split][bh][d][l] = sum_{n in split} k[b,n,h*128+d] * v[b,n,h*128+l]
constexpr int ATT_SPLIT = 4;
__global__ __launch_bounds__(256) void att_kernel(const bf16* __restrict__ key,
                                                  const bf16* __restrict__ v,
                                                  float* __restrict__ att_part) {
    int bh = blockIdx.x;
    int b = bh >> 3, h = bh & 7;
    int split = blockIdx.y;
    const bf16* kb = key + (long)b * Nc * Dc + h * 128;
    const bf16* vb = v + (long)b * Nc * Dc + h * 128;
    float* ap = att_part + ((long)split * 64 + bh) * 16384;
    const int per = (Nc + ATT_SPLIT - 1) / ATT_SPLIT;  // 532
    int n0 = split * per, n1 = min(Nc, n0 + per);
    __shared__ float ks[16][128], vs[16][128];
    int tid = threadIdx.x, tx = tid & 15, ty = tid >> 4;
    float acc[8][8] = {};
    for (int nb = n0; nb < n1; nb += 16) {
        int nc = min(16, n1 - nb);
        for (int e = tid; e < 2048; e += 256) {
            int nn = e >> 7, d = e & 127;
            float kvv = 0.f, vvv = 0.f;
            if (nn < nc) {
                long off = (long)(nb + nn) * Dc + d;
                kvv = b2f(kb[off]); vvv = b2f(vb[off]);
            }
            ks[nn][d] = kvv; vs[nn][d] = vvv;
        }
        __syncthreads();
        #pragma unroll
        for (int nn = 0; nn < 16; ++nn) {
            float kr[8], vr[8];
            #pragma unroll
            for (int i = 0; i < 8; ++i) kr[i] = ks[nn][ty * 8 + i];
            #pragma unroll
            for (int j = 0; j < 8; ++j) vr[j] = vs[nn][tx * 8 + j];
            #pragma unroll
            for (int i = 0; i < 8; ++i)
                #pragma unroll
                for (int j = 0; j < 8; ++j)
                    acc[i][j] = fmaf(kr[i], vr[j], acc[i][j]);
        }
        __syncthreads();
    }
    for (int i = 0; i < 8; ++i)
        for (int j = 0; j < 8; ++j)
            ap[(ty * 8 + i) * 128 + tx * 8 + j] = acc[i][j];
}

__global__ __launch_bounds__(256) void reduce_att(const float* __restrict__ att_part,
                                                  float* __restrict__ att) {
    long idx = (long)blockIdx.x * 256 + threadIdx.x;
    if (idx >= (long)64 * 16384) return;
    float s = 0.f;
    #pragma unroll
    for (int sp = 0; sp < ATT_SPLIT; ++sp) s += att_part[(long)sp * 64 * 16384 + idx];
    att[idx] = s;
}

// y[b,t,h*128+l] = sum_d q[b,t,h*128+d] * att[bh][d][l]
__global__ __launch_bounds__(256) void y_kernel(const bf16* __restrict__ q,
                                                const float* __restrict__ att,
                                                bf16* __restrict__ y) {
    int bh = blockIdx.y;
    int b = bh >> 3, h = bh & 7;
    const bf16* qb = q + (long)b * Tc * Dc + h * 128;
    const float* ab = att + (long)bh * 16384;
    bf16* yb = y + (long)b * Tc * Dc + h * 128;
    int t0 = blockIdx.x * 64;
    __shared__ float qs[16][68];
    __shared__ float as[16][128];
    int tid = threadIdx.x, tx = tid & 15, ty = tid >> 4;
    float acc[4][8] = {};
    for (int k0 = 0; k0 < 128; k0 += 16) {
        for (int e = tid; e < 1024; e += 256) {
            int m = e >> 4, k = e & 15;
            qs[k][m] = b2f(qb[(long)(t0 + m) * Dc + k0 + k]);
        }
        for (int e = tid; e < 2048; e += 256) {
            int k = e >> 7, n = e & 127;
            as[k][n] = ab[(k0 + k) * 128 + n];
        }
        __syncthreads();
        #pragma unroll
        for (int k = 0; k < 16; ++k) {
            float a[4], w[8];
            #pragma unroll
            for (int i = 0; i < 4; ++i) a[i] = qs[k][ty * 4 + i];
            #pragma unroll
            for (int j = 0; j < 8; ++j) w[j] = as[k][tx * 8 + j];
            #pragma unroll
            for (int i = 0; i < 4; ++i)
                #pragma unroll
                for (int j = 0; j < 8; ++j)
                    acc[i][j] = fmaf(a[i], w[j], acc[i][j]);
        }
        __syncthreads();
    }
    for (int i = 0; i < 4; ++i)
        for (int j = 0; j < 8; ++j)
            yb[(long)(t0 + ty * 4 + i) * Dc + tx * 8 + j] = f2b(acc[i][j]);
}

__global__ __launch_bounds__(256) void silu_kernel(const float* __restrict__ in,
                                                   float* __restrict__ out, int n) {
    int i = blockIdx.x * 256 + threadIdx.x;
    if (i < n) { float v = in[i]; out[i] = v / (1.f + expf(-v)); }
}

// s = silu( LN(y)*(1+scale) + shift )
__global__ __launch_bounds__(256) void film_kernel(const bf16* __restrict__ y,
                                                   const float* __restrict__ eo,
                                                   const float* __restrict__ g,
                                                   const float* __restrict__ bta,
                                                   bf16* __restrict__ s) {
    long row = blockIdx.x;
    int b = (int)(row >> 10);
    const bf16* yr = y + row * Dc;
    float sum = 0.f, sum2 = 0.f;
    for (int c = threadIdx.x; c < Dc; c += 256) { float v = b2f(yr[c]); sum += v; sum2 += v * v; }
    float2 r = block_sum2(sum, sum2);
    float mean = r.x / Dc;
    float var = r.y / Dc - mean * mean;
    float inv = rsqrtf(var + 1e-5f);
    const float* sc = eo + (long)b * 2048;
    const float* sf = sc + 1024;
    bf16* so = s + row * Dc;
    for (int c = threadIdx.x; c < Dc; c += 256) {
        float v = (b2f(yr[c]) - mean) * inv * g[c] + bta[c];
        v = v * (1.f + sc[c]) + sf[c];
        so[c] = f2b(v / (1.f + expf(-v)));
    }
}

extern "C" void kernel_launch(void* const* d_in, const int* in_sizes, int n_in,
                              void* d_out, int out_size, void* d_ws, size_t ws_size,
                              hipStream_t stream) {
    if (ws_size < WS_NEED) return;  // visible absmax fail instead of a crash

    const float* x         = (const float*)d_in[0];
    const float* xf        = (const float*)d_in[1];
    const float* emb       = (const float*)d_in[2];
    const float* src_mask  = (const float*)d_in[3];
    const int*   cond_type = (const int*)d_in[4];
    const float* re_motion = (const float*)d_in[5];
    const float* re_text   = (const float*)d_in[6];
    const float* re_mask   = (const float*)d_in[7];
    const float* ln_g  = (const float*)d_in[8];
    const float* ln_b  = (const float*)d_in[9];
    const float* tln_g = (const float*)d_in[10];
    const float* tln_b = (const float*)d_in[11];
    const float* rn1_g = (const float*)d_in[12];
    const float* rn1_b = (const float*)d_in[13];
    const float* rn2_g = (const float*)d_in[14];
    const float* rn2_b = (const float*)d_in[15];
    const float* Wq  = (const float*)d_in[16];
    const float* bq  = (const float*)d_in[17];
    const float* Wkt = (const float*)d_in[18];
    const float* bkt = (const float*)d_in[19];
    const float* Wvt = (const float*)d_in[20];
    const float* bvt = (const float*)d_in[21];
    const float* Wkm = (const float*)d_in[22];
    const float* bkm = (const float*)d_in[23];
    const float* Wvm = (const float*)d_in[24];
    const float* bvm = (const float*)d_in[25];
    const float* Wkr = (const float*)d_in[26];
    const float* bkr = (const float*)d_in[27];
    const float* Wvr = (const float*)d_in[28];
    const float* bvr = (const float*)d_in[29];
    const float* We  = (const float*)d_in[30];
    const float* be  = (const float*)d_in[31];
    const float* sln_g = (const float*)d_in[32];
    const float* sln_b = (const float*)d_in[33];
    const float* Wo  = (const float*)d_in[34];
    const float* bo  = (const float*)d_in[35];

    float* ws = (float*)d_ws;
    float* stats1   = ws + F_STATS1;
    float* stats2   = ws + F_STATS2;
    float* key_add  = ws + F_KEYADD;
    float* val_mul  = ws + F_VALMUL;
    float* silu_emb = ws + F_SILU;
    float* eo       = ws + F_EO;
    float* att      = ws + F_ATT;
    bf16* wb = (bf16*)(ws + F_END);
    bf16* norm_x16 = wb + B_NORMX;
    bf16* q16      = wb + B_Q;
    bf16* key16    = wb + B_KEY;
    bf16* v16      = wb + B_V;
    bf16* nxf16    = wb + B_NXF;
    short* WtQ  = (short*)(wb + B_WQ);
    short* WtKT = (short*)(wb + B_WKT);
    short* WtVT = (short*)(wb + B_WVT);
    short* WtKM = (short*)(wb + B_WKM);
    short* WtVM = (short*)(wb + B_WVM);
    short* WtKR = (short*)(wb + B_WKR);
    short* WtVR = (short*)(wb + B_WVR);
    short* WtO  = (short*)(wb + B_WO);
    float* att_part = (float*)(wb + B_NORMX);  // overlays norm_x16 (dead by then)
    bf16* y16 = wb + B_NORMX;                  // written after att_part consumed
    bf16* s16 = q16;                           // q dead after y_kernel

    float* out = (float*)d_out;
    const long sKey = (long)Nc * Dc;

    // 1. LayerNorms + stats
    ln_rows<bf16><<<dim3(Bc * Tc), dim3(256), 0, stream>>>(x, ln_g, ln_b, norm_x16, Dc);
    ln_rows<bf16><<<dim3(Bc * NTc), dim3(256), 0, stream>>>(xf, tln_g, tln_b, nxf16, LTc);
    ln_stats_cat<<<dim3(Bc * KRc), dim3(256), 0, stream>>>(re_motion, re_text, stats1);
    ln_stats_rows<<<dim3(Bc * KRc), dim3(256), 0, stream>>>(re_motion, stats2);

    // 2. Masks
    prep_masks<<<dim3((Bc * Nc + 255) / 256), dim3(256), 0, stream>>>(
        cond_type, src_mask, re_mask, key_add, val_mul);

    // 3. Weight transposes (fp32 [K][N] -> bf16 [N][K])
    transpose_w<<<dim3(32, 32), dim3(256), 0, stream>>>(Wq, WtQ, 1024, 1024);
    transpose_w<<<dim3(32, 24), dim3(256), 0, stream>>>(Wkt, WtKT, 768, 1024);
    transpose_w<<<dim3(32, 24), dim3(256), 0, stream>>>(Wvt, WtVT, 768, 1024);
    transpose_w<<<dim3(32, 32), dim3(256), 0, stream>>>(Wkm, WtKM, 1024, 1024);
    transpose_w<<<dim3(32, 32), dim3(256), 0, stream>>>(Wvm, WtVM, 1024, 1024);
    transpose_w<<<dim3(32, 64), dim3(256), 0, stream>>>(Wkr, WtKR, 2048, 1024);
    transpose_w<<<dim3(32, 32), dim3(256), 0, stream>>>(Wvr, WtVR, 1024, 1024);
    transpose_w<<<dim3(32, 32), dim3(256), 0, stream>>>(Wo, WtO, 1024, 1024);

    // 4. MFMA GEMMs
    // query = norm_x @ Wq + bq  (flat M=8192)
    gemm_bt<bf16><<<dim3(8, 64, 1), dim3(256), 0, stream>>>(
        (const short*)norm_x16, Dc, 0, WtQ, 1024, bq, nullptr, 0, nullptr, 0,
        nullptr, 0, 0, q16, Dc, 0, Bc * Tc, 1024);
    // key_text
    gemm_bt<bf16><<<dim3(8, 1, Bc), dim3(256), 0, stream>>>(
        (const short*)nxf16, LTc, (long)NTc * LTc, WtKT, 768, bkt,
        key_add + 0, Nc, nullptr, 0, nullptr, 0, 0,
        key16 + 0, Dc, sKey, NTc, 768);
    // key_retr (LN fused, K=2048)
    gemm_lnA_mfma<bf16><<<dim3(8, 8, Bc), dim3(256), 0, stream>>>(
        re_motion, re_text, stats1, rn1_g, rn1_b, WtKR, 2048, bkr,
        key_add + NTc, Nc, nullptr, 0, key16 + (long)NTc * Dc, Dc, sKey, 2048);
    // key_motion
    gemm_bt<bf16><<<dim3(8, 8, Bc), dim3(256), 0, stream>>>(
        (const short*)norm_x16, Dc, (long)Tc * Dc, WtKM, 1024, bkm,
        key_add + NTc + KRc, Nc, nullptr, 0, nullptr, 0, 0,
        key16 + (long)(NTc + KRc) * Dc, Dc, sKey, Tc, 1024);
    // value_text
    gemm_bt<bf16><<<dim3(8, 1, Bc), dim3(256), 0, stream>>>(
        (const short*)nxf16, LTc, (long)NTc * LTc, WtVT, 768, bvt,
        nullptr, 0, val_mul + 0, Nc, nullptr, 0, 0,
        v16 + 0, Dc, sKey, NTc, 768);
    // value_retr (LN fused, K=1024)
    gemm_lnA_mfma<bf16><<<dim3(8, 8, Bc), dim3(256), 0, stream>>>(
        re_motion, nullptr, stats2, rn2_g, rn2_b, WtVR, 1024, bvr,
        nullptr, 0, val_mul + NTc, Nc, v16 + (long)NTc * Dc, Dc, sKey, 1024);
    // value_motion
    gemm_bt<bf16><<<dim3(8, 8, Bc), dim3(256), 0, stream>>>(
        (const short*)norm_x16, Dc, (long)Tc * Dc, WtVM, 1024, bvm,
        nullptr, 0, val_mul + NTc + KRc, Nc, nullptr, 0, 0,
        v16 + (long)(NTc + KRc) * Dc, Dc, sKey, Tc, 1024);

    // 5. Softmaxes
    softmax_head<<<dim3(Bc * Tc * Hc), dim3(128), 0, stream>>>(q16);
    softmax_tokens<<<dim3(Dc / 64, Bc), dim3(256), 0, stream>>>(key16);

    // 6. att = k^T v (split over N, then reduce); att_part overlays norm_x region
    att_kernel<<<dim3(Bc * Hc, ATT_SPLIT), dim3(256), 0, stream>>>(key16, v16, att_part);
    reduce_att<<<dim3((64 * 16384 + 255) / 256), dim3(256), 0, stream>>>(att_part, att);

    // 7. y = q @ att  (writes over att_part region — att_part fully consumed)
    y_kernel<<<dim3(Tc / 64, Bc * Hc), dim3(256), 0, stream>>>(q16, att, y16);

    // 8. Time-embedding FiLM params
    silu_kernel<<<dim3((Bc * Ec + 255) / 256), dim3(256), 0, stream>>>(emb, silu_emb, Bc * Ec);
    gemm_ep<<<dim3(32, 1, 1), dim3(256), 0, stream>>>(
        silu_emb, Ec, We, 2048, be, eo, 2048, Bc, Ec);

    // 9. FiLM + silu (s overlays q region)
    film_kernel<<<dim3(Bc * Tc), dim3(256), 0, stream>>>(y16, eo, sln_g, sln_b, s16);

    // 10. out = x + s @ Wo + bo
    gemm_bt<float><<<dim3(8, 64, 1), dim3(256), 0, stream>>>(
        (const short*)s16, Dc, 0, WtO, 1024, bo, nullptr, 0, nullptr, 0,
        x, Dc, 0, out, Dc, 0, Bc * Tc, 1024);
}

// Round 4
// 1226.931 us; speedup vs baseline: 2.7628x; 1.5086x over previous
//
#include <hip/hip_runtime.h>
#include <hip/hip_bf16.h>
#include <math.h>

using bf16 = __hip_bfloat16;

typedef short s16x8 __attribute__((ext_vector_type(8)));
typedef float f32x4 __attribute__((ext_vector_type(4)));

// Problem dims (fixed by setup_inputs)
constexpr int Bc = 8, Tc = 1024, Dc = 1024, Hc = 8;
constexpr int NTc = 77, LTc = 768, KRc = 1024, Nc = 2125, Ec = 2048;
constexpr float NEGC = -1000000.0f;

// ---- Workspace layout (unchanged from passing R3 run: WS_NEED ~126.6 MB) ----
constexpr long F_STATS1 = 0;                    // 16,384
constexpr long F_STATS2 = F_STATS1 + 16384;     // 16,384
constexpr long F_KEYADD = F_STATS2 + 16384;     // 17,000
constexpr long F_VALMUL = F_KEYADD + 17000;     // 17,000
constexpr long F_SILU   = F_VALMUL + 17000;     // 16,384 (unused now; kept for layout stability)
constexpr long F_EO     = F_SILU + 16384;       // 16,384
constexpr long F_ATT    = F_EO + 16384;         // 1,048,576
constexpr long F_END    = F_ATT + 1048576;
// bf16 region
constexpr long B_NORMX = 0;                     // 8,388,608 (reused: att_part fp32, then y16)
constexpr long B_Q     = B_NORMX + 8388608;     // 8,388,608 (reused: s16)
constexpr long B_KEY   = B_Q + 8388608;         // 17,408,000
constexpr long B_V     = B_KEY + 17408000;      // 17,408,000 (reused: eo_part fp32 after att)
constexpr long B_NXF   = B_V + 17408000;        // 473,088
constexpr long B_WQ    = B_NXF + 473088;
constexpr long B_WKT   = B_WQ + 1048576;
constexpr long B_WVT   = B_WKT + 786432;
constexpr long B_WKM   = B_WVT + 786432;
constexpr long B_WVM   = B_WKM + 1048576;
constexpr long B_WKR   = B_WVM + 1048576;
constexpr long B_WVR   = B_WKR + 2097152;
constexpr long B_WO    = B_WVR + 1048576;
constexpr long B_END   = B_WO + 1048576;
constexpr size_t WS_NEED = (size_t)F_END * 4 + (size_t)B_END * 2;

__device__ __forceinline__ float b2f(bf16 v) { return __bfloat162float(v); }
__device__ __forceinline__ bf16 f2b(float v) { return __float2bfloat16(v); }
__device__ __forceinline__ short f2s(float v) {
    bf16 h = __float2bfloat16(v);
    return *reinterpret_cast<short*>(&h);
}
__device__ __forceinline__ void storef(float* p, float v) { *p = v; }
__device__ __forceinline__ void storef(bf16* p, float v) { *p = __float2bfloat16(v); }

// async global->LDS, 16B per lane. LDS dest must be wave-uniform base + lane*16.
typedef __attribute__((address_space(1))) const unsigned int gu32;
typedef __attribute__((address_space(3))) unsigned int lu32;
__device__ __forceinline__ void gl_lds16(const void* g, void* l) {
    __builtin_amdgcn_global_load_lds((gu32*)g, (lu32*)l, 16, 0, 0);
}

__device__ __forceinline__ float2 block_sum2(float s, float s2) {
    #pragma unroll
    for (int off = 32; off > 0; off >>= 1) {
        s  += __shfl_down(s, off, 64);
        s2 += __shfl_down(s2, off, 64);
    }
    __shared__ float sh[4], sh2[4];
    int w = threadIdx.x >> 6, lane = threadIdx.x & 63;
    if (lane == 0) { sh[w] = s; sh2[w] = s2; }
    __syncthreads();
    s = sh[0] + sh[1] + sh[2] + sh[3];
    s2 = sh2[0] + sh2[1] + sh2[2] + sh2[3];
    return make_float2(s, s2);
}

// Row LayerNorm: one block (256 thr) per row
template <typename TO>
__global__ __launch_bounds__(256) void ln_rows(const float* __restrict__ in,
                                               const float* __restrict__ g,
                                               const float* __restrict__ b,
                                               TO* __restrict__ out, int C) {
    long row = blockIdx.x;
    const float* x = in + row * (long)C;
    TO* o = out + row * (long)C;
    float s = 0.f, s2 = 0.f;
    for (int c = threadIdx.x; c < C; c += 256) { float v = x[c]; s += v; s2 += v * v; }
    float2 r = block_sum2(s, s2);
    float mean = r.x / C;
    float var = r.y / C - mean * mean;
    float inv = rsqrtf(var + 1e-5f);
    for (int c = threadIdx.x; c < C; c += 256)
        storef(&o[c], (x[c] - mean) * inv * g[c] + b[c]);
}

// Both retrieval LN stats in one pass over re_motion:
// stats2 = LN stats of motion row (1024); stats1 = LN stats of concat(motion,text) (2048)
__global__ __launch_bounds__(256) void ln_stats_both(const float* __restrict__ motion,
                                                     const float* __restrict__ text,
                                                     float* __restrict__ stats1,
                                                     float* __restrict__ stats2) {
    long row = blockIdx.x;  // b*1024 + k*512 + r
    const float* m = motion + row * 1024;
    const float* tx = text + (row >> 9) * 1024;
    float s = 0.f, s2 = 0.f;
    for (int c = threadIdx.x; c < 1024; c += 256) { float v = m[c]; s += v; s2 += v * v; }
    float2 rm = block_sum2(s, s2);
    __syncthreads();  // protect shared reduce buffers before reuse
    float st = 0.f, st2 = 0.f;
    for (int c = threadIdx.x; c < 1024; c += 256) { float v = tx[c]; st += v; st2 += v * v; }
    float2 rt = block_sum2(st, st2);
    if (threadIdx.x == 0) {
        float mean2 = rm.x / 1024.f;
        float var2 = rm.y / 1024.f - mean2 * mean2;
        stats2[2 * row] = mean2;
        stats2[2 * row + 1] = rsqrtf(var2 + 1e-5f);
        float mean1 = (rm.x + rt.x) / 2048.f;
        float var1 = (rm.y + rt.y) / 2048.f - mean1 * mean1;
        stats1[2 * row] = mean1;
        stats1[2 * row + 1] = rsqrtf(var1 + 1e-5f);
    }
}

// Per-(b, n) key additive mask and value multiplicative mask
__global__ __launch_bounds__(256) void prep_masks(const int* __restrict__ cond_type,
                                                  const float* __restrict__ src_mask,
                                                  const float* __restrict__ re_mask,
                                                  float* __restrict__ key_add,
                                                  float* __restrict__ val_mul) {
    int idx = blockIdx.x * 256 + threadIdx.x;
    if (idx >= Bc * Nc) return;
    int b = idx / Nc, n = idx % Nc;
    int ct = cond_type[b];
    float text_ct = ((ct % 10) > 0) ? 1.f : 0.f;
    float retr_ct = ((ct / 10) > 0) ? 1.f : 0.f;
    float add, mul;
    if (n < NTc) {
        add = (1.f - text_ct) * NEGC; mul = text_ct;
    } else if (n < NTc + KRc) {
        float rm = re_mask[b * KRc + (n - NTc)];
        add = (1.f - retr_ct) * NEGC + (1.f - rm) * NEGC;
        mul = retr_ct * rm;
    } else {
        float sm = src_mask[b * Tc + (n - NTc - KRc)];
        add = (1.f - sm) * NEGC; mul = sm;
    }
    key_add[idx] = add;
    val_mul[idx] = mul;
}

// Transpose + convert weight: W[K][N] fp32 -> Wt[N][K] bf16(short)
__global__ __launch_bounds__(256) void transpose_w(const float* __restrict__ W,
                                                   short* __restrict__ Wt,
                                                   int K, int N) {
    __shared__ float t[32][33];
    int n0 = blockIdx.x * 32, k0 = blockIdx.y * 32;
    int tx = threadIdx.x & 31, ty = threadIdx.x >> 5;
    #pragma unroll
    for (int i = 0; i < 4; ++i)
        t[ty + i * 8][tx] = W[(long)(k0 + ty + i * 8) * N + n0 + tx];
    __syncthreads();
    #pragma unroll
    for (int i = 0; i < 4; ++i)
        Wt[(long)(n0 + ty + i * 8) * K + k0 + tx] = f2s(t[tx][ty + i * 8]);
}

// ======================= MFMA GEMM (B^T layout, async LDS staging) ==========
// 128x128 tile, BK=64, 256 thr = 4 waves (2x2 of 64x64), 16x16x32 bf16 MFMA.
// LDS row stride MUST be 64 (=BK): global_load_lds lands at waveBase + lane*16.
constexpr int LDK = 64;

template <typename TC>
__global__ __launch_bounds__(256) void gemm_bt(
    const short* __restrict__ A, int lda, long sA,
    const short* __restrict__ Bt, int ldb,
    const float* __restrict__ bias,
    const float* __restrict__ rowadd, int sRA,
    const float* __restrict__ rowmul, int sRM,
    const float* __restrict__ addC, int ldac, long sAC,
    TC* __restrict__ C, int ldc, long sC,
    int M, int K) {
    int bz = blockIdx.z;
    A += (long)bz * sA;
    C += (long)bz * sC;
    if (rowadd) rowadd += (long)bz * sRA;
    if (rowmul) rowmul += (long)bz * sRM;
    if (addC) addC += (long)bz * sAC;

    const int tm = blockIdx.y * 128;
    const int tn = blockIdx.x * 128;

    __shared__ __align__(16) short As[128 * LDK];
    __shared__ __align__(16) short Bs[128 * LDK];

    int tid = threadIdx.x;
    int lane = tid & 63, wid = tid >> 6;
    int wi = wid >> 1, wj = wid & 1;
    int l16 = lane & 15, quad = lane >> 4;

    f32x4 acc[4][4];
    #pragma unroll
    for (int i = 0; i < 4; ++i)
        #pragma unroll
        for (int j = 0; j < 4; ++j)
            acc[i][j] = (f32x4){0.f, 0.f, 0.f, 0.f};

    auto issue = [&](int k0) {
        #pragma unroll
        for (int p = 0; p < 4; ++p) {
            int e = p * 256 + tid;
            int row = e >> 3, c8 = e & 7;
            int gm = tm + row;
            if (gm >= M) gm = M - 1;  // clamp: garbage rows never stored
            gl_lds16(A + (long)gm * lda + k0 + c8 * 8, &As[row * LDK + c8 * 8]);
            gl_lds16(Bt + (long)(tn + row) * ldb + k0 + c8 * 8, &Bs[row * LDK + c8 * 8]);
        }
    };

    issue(0);
    int kt = 0;
    while (true) {
        __syncthreads();  // drains vmcnt(0): LDS tiles ready
        #pragma unroll
        for (int kk = 0; kk < 2; ++kk) {
            s16x8 af[4], bfr[4];
            #pragma unroll
            for (int i = 0; i < 4; ++i)
                af[i] = *(const s16x8*)&As[(wi * 64 + i * 16 + l16) * LDK + kk * 32 + quad * 8];
            #pragma unroll
            for (int j = 0; j < 4; ++j)
                bfr[j] = *(const s16x8*)&Bs[(wj * 64 + j * 16 + l16) * LDK + kk * 32 + quad * 8];
            #pragma unroll
            for (int i = 0; i < 4; ++i)
                #pragma unroll
                for (int j = 0; j < 4; ++j)
                    acc[i][j] = __builtin_amdgcn_mfma_f32_16x16x32_bf16(af[i], bfr[j], acc[i][j], 0, 0, 0);
        }
        int nxt = kt + 64;
        if (nxt >= K) break;
        __syncthreads();  // all waves done reading before overwrite
        issue(nxt);
        kt = nxt;
    }

    #pragma unroll
    for (int i = 0; i < 4; ++i) {
        #pragma unroll
        for (int r = 0; r < 4; ++r) {
            int gm = tm + wi * 64 + i * 16 + quad * 4 + r;
            if (gm >= M) continue;
            float ra = rowadd ? rowadd[gm] : 0.f;
            float rm = rowmul ? rowmul[gm] : 1.f;
            #pragma unroll
            for (int j = 0; j < 4; ++j) {
                int gn = tn + wj * 64 + j * 16 + l16;
                float v = acc[i][j][r] + (bias ? bias[gn] : 0.f) + ra;
                v *= rm;
                if (addC) v += addC[(long)gm * ldac + gn];
                storef(&C[(long)gm * ldc + gn], v);
            }
        }
    }
}

// MFMA GEMM with LayerNorm fused into A staging (A via regs->LDS, B async).
template <typename TC>
__global__ __launch_bounds__(256) void gemm_lnA_mfma(
    const float* __restrict__ motion, const float* __restrict__ text,
    const float* __restrict__ stats,
    const float* __restrict__ g, const float* __restrict__ bvec,
    const short* __restrict__ Bt, int ldb,
    const float* __restrict__ bias,
    const float* __restrict__ rowadd, int sRA,
    const float* __restrict__ rowmul, int sRM,
    TC* __restrict__ C, int ldc, long sC,
    int K) {
    int bz = blockIdx.z;
    C += (long)bz * sC;
    if (rowadd) rowadd += (long)bz * sRA;
    if (rowmul) rowmul += (long)bz * sRM;

    const int tm = blockIdx.y * 128;
    const int tn = blockIdx.x * 128;

    __shared__ __align__(16) short As[128 * LDK];
    __shared__ __align__(16) short Bs[128 * LDK];

    int tid = threadIdx.x;
    int lane = tid & 63, wid = tid >> 6;
    int wi = wid >> 1, wj = wid & 1;
    int l16 = lane & 15, quad = lane >> 4;

    f32x4 acc[4][4];
    #pragma unroll
    for (int i = 0; i < 4; ++i)
        #pragma unroll
        for (int j = 0; j < 4; ++j)
            acc[i][j] = (f32x4){0.f, 0.f, 0.f, 0.f};

    uint4 pa[4];

    auto computeA = [&](int k0) {
        #pragma unroll
        for (int p = 0; p < 4; ++p) {
            int e = p * 256 + tid;
            int row = e >> 3, c8 = e & 7;
            long rg = (long)bz * 1024 + tm + row;
            int c = k0 + c8 * 8;
            const float* src = (c < 1024) ? motion + rg * 1024 + c
                                          : text + (rg >> 9) * 1024 + (c - 1024);
            float4 v0 = *(const float4*)src;
            float4 v1 = *(const float4*)(src + 4);
            float mean = stats[2 * rg], rstd = stats[2 * rg + 1];
            float4 g0 = *(const float4*)&g[c], g1 = *(const float4*)&g[c + 4];
            float4 b0 = *(const float4*)&bvec[c], b1 = *(const float4*)&bvec[c + 4];
            union { short s[8]; uint4 u; } pk;
            pk.s[0] = f2s((v0.x - mean) * rstd * g0.x + b0.x);
            pk.s[1] = f2s((v0.y - mean) * rstd * g0.y + b0.y);
            pk.s[2] = f2s((v0.z - mean) * rstd * g0.z + b0.z);
            pk.s[3] = f2s((v0.w - mean) * rstd * g0.w + b0.w);
            pk.s[4] = f2s((v1.x - mean) * rstd * g1.x + b1.x);
            pk.s[5] = f2s((v1.y - mean) * rstd * g1.y + b1.y);
            pk.s[6] = f2s((v1.z - mean) * rstd * g1.z + b1.z);
            pk.s[7] = f2s((v1.w - mean) * rstd * g1.w + b1.w);
            pa[p] = pk.u;
        }
    };
    auto issueB = [&](int k0) {
        #pragma unroll
        for (int p = 0; p < 4; ++p) {
            int e = p * 256 + tid;
            int row = e >> 3, c8 = e & 7;
            gl_lds16(Bt + (long)(tn + row) * ldb + k0 + c8 * 8, &Bs[row * LDK + c8 * 8]);
        }
    };
    auto storeA = [&]() {
        #pragma unroll
        for (int p = 0; p < 4; ++p) {
            int e = p * 256 + tid;
            int row = e >> 3, c8 = e & 7;
            *(uint4*)&As[row * LDK + c8 * 8] = pa[p];
        }
    };

    issueB(0);
    computeA(0);
    storeA();
    int kt = 0;
    while (true) {
        __syncthreads();  // drains vmcnt + lgkm: both tiles ready
        #pragma unroll
        for (int kk = 0; kk < 2; ++kk) {
            s16x8 af[4], bfr[4];
            #pragma unroll
            for (int i = 0; i < 4; ++i)
                af[i] = *(const s16x8*)&As[(wi * 64 + i * 16 + l16) * LDK + kk * 32 + quad * 8];
            #pragma unroll
            for (int j = 0; j < 4; ++j)
                bfr[j] = *(const s16x8*)&Bs[(wj * 64 + j * 16 + l16) * LDK + kk * 32 + quad * 8];
            #pragma unroll
            for (int i = 0; i < 4; ++i)
                #pragma unroll
                for (int j = 0; j < 4; ++j)
                    acc[i][j] = __builtin_amdgcn_mfma_f32_16x16x32_bf16(af[i], bfr[j], acc[i][j], 0, 0, 0);
        }
        int nxt = kt + 64;
        if (nxt >= K) break;
        computeA(nxt);    // global fp32 loads overlap the tail of compute
        __syncthreads();  // all waves done reading LDS
        issueB(nxt);
        storeA();
        kt = nxt;
    }

    #pragma unroll
    for (int i = 0; i < 4; ++i) {
        #pragma unroll
        for (int r = 0; r < 4; ++r) {
            int gm = tm + wi * 64 + i * 16 + quad * 4 + r;
            float ra = rowadd ? rowadd[gm] : 0.f;
            float rm = rowmul ? rowmul[gm] : 1.f;
            #pragma unroll
            for (int j = 0; j < 4; ++j) {
                int gn = tn + wj * 64 + j * 16 + l16;
                float v = acc[i][j][r] + (bias ? bias[gn] : 0.f) + ra;
                v *= rm;
                storef(&C[(long)gm * ldc + gn], v);
            }
        }
    }
}

// eo split-K: partial[ks][b][n] = sum_{k in split} silu(emb[b][k]) * We[k][n]
__global__ __launch_bounds__(256) void eo_partial(const float* __restrict__ emb,
                                                  const float* __restrict__ We,
                                                  float* __restrict__ part) {
    int nb = blockIdx.x;   // 8 col chunks of 256
    int ks = blockIdx.y;   // 32 k-splits of 64
    int n = nb * 256 + threadIdx.x;
    int k0 = ks * 64;
    __shared__ float a_s[8][64];
    for (int idx = threadIdx.x; idx < 512; idx += 256) {
        int b = idx >> 6, kk = idx & 63;
        float v = emb[b * 2048 + k0 + kk];
        a_s[b][kk] = v / (1.f + expf(-v));
    }
    __syncthreads();
    float acc[8] = {};
    for (int kk = 0; kk < 64; ++kk) {
        float w = We[(long)(k0 + kk) * 2048 + n];
        #pragma unroll
        for (int b = 0; b < 8; ++b) acc[b] = fmaf(a_s[b][kk], w, acc[b]);
    }
    #pragma unroll
    for (int b = 0; b < 8; ++b) part[((long)ks * 8 + b) * 2048 + n] = acc[b];
}

__global__ __launch_bounds__(256) void eo_reduce(const float* __restrict__ part,
                                                 const float* __restrict__ be,
                                                 float* __restrict__ eo) {
    int idx = blockIdx.x * 256 + threadIdx.x;  // 16384 = b*2048+n
    int n = idx & 2047, b = idx >> 11;
    float s = be[n];
    #pragma unroll 8
    for (int ks = 0; ks < 32; ++ks) s += part[((long)ks * 8 + b) * 2048 + n];
    eo[idx] = s;
}

// q softmax over head dim (128): one wave per row, 2 elems/lane, shuffle reduce.
__global__ __launch_bounds__(256) void softmax_head(bf16* __restrict__ q) {
    long row = (long)blockIdx.x * 4 + (threadIdx.x >> 6);
    int lane = threadIdx.x & 63;
    bf16* p = q + row * 128 + lane * 2;
    float v0 = b2f(p[0]), v1 = b2f(p[1]);
    float mx = fmaxf(v0, v1);
    #pragma unroll
    for (int off = 32; off > 0; off >>= 1) mx = fmaxf(mx, __shfl_xor(mx, off, 64));
    float e0 = expf(v0 - mx), e1 = expf(v1 - mx);
    float s = e0 + e1;
    #pragma unroll
    for (int off = 32; off > 0; off >>= 1) s += __shfl_xor(s, off, 64);
    float inv = 1.f / s;
    p[0] = f2b(e0 * inv);
    p[1] = f2b(e1 * inv);
}

// k softmax over tokens (N=2125) per column, bf16 in place.
__global__ __launch_bounds__(256) void softmax_tokens(bf16* __restrict__ key) {
    int b = blockIdx.y;
    int lane = threadIdx.x & 63;
    int ch = threadIdx.x >> 6;
    int c = blockIdx.x * 64 + lane;
    bf16* kp = key + (long)b * Nc * Dc + c;
    const int per = (Nc + 3) / 4;  // 532
    int n0 = ch * per, n1 = min(Nc, n0 + per);
    float mx = -3.0e38f;
    for (int n = n0; n < n1; ++n) mx = fmaxf(mx, b2f(kp[(long)n * Dc]));
    __shared__ float redm[4][64];
    redm[ch][lane] = mx; __syncthreads();
    mx = fmaxf(fmaxf(redm[0][lane], redm[1][lane]), fmaxf(redm[2][lane], redm[3][lane]));
    float sum = 0.f;
    for (int n = n0; n < n1; ++n) {
        long idx = (long)n * Dc;
        float e = expf(b2f(kp[idx]) - mx);
        sum += e;
        kp[idx] = f2b(e);  // store unscaled exp; scale in pass 3
    }
    __shared__ float reds[4][64];
    reds[ch][lane] = sum; __syncthreads();
    sum = reds[0][lane] + reds[1][lane] + reds[2][lane] + reds[3][lane];
    float inv = 1.f / sum;
    for (int n = n0; n < n1; ++n) {
        long idx = (long)n * Dc;
        kp[idx] = f2b(b2f(kp[idx]) * inv);
    }
}

// att_part[split][bh][d][l] = sum_{n in split} k[b,n,h*128+d] * v[b,n,h*128+l]
constexpr int ATT_SPLIT = 4;
__global__ __launch_bounds__(256) void att_kernel(const bf16* __restrict__ key,
                                                  const bf16* __restrict__ v,
                                                  float* __restrict__ att_part) {
    int bh = blockIdx.x;
    int b = bh >> 3, h = bh & 7;
    int split = blockIdx.y;
    const bf16* kb = key + (long)b * Nc * Dc + h * 128;
    const bf16* vb = v + (long)b * Nc * Dc + h * 128;
    float* ap = att_part + ((long)split * 64 + bh) * 16384;
    const int per = (Nc + ATT_SPLIT - 1) / ATT_SPLIT;  // 532
    int n0 = split * per, n1 = min(Nc, n0 + per);
    __shared__ float ks[16][128], vs[16][128];
    int tid = threadIdx.x, tx = tid & 15, ty = tid >> 4;
    float acc[8][8] = {};
    for (int nb = n0; nb < n1; nb += 16) {
        int nc = min(16, n1 - nb);
        for (int e = tid; e < 2048; e += 256) {
            int nn = e >> 7, d = e & 127;
            float kvv = 0.f, vvv = 0.f;
            if (nn < nc) {
                long off = (long)(nb + nn) * Dc + d;
                kvv = b2f(kb[off]); vvv = b2f(vb[off]);
            }
            ks[nn][d] = kvv; vs[nn][d] = vvv;
        }
        __syncthreads();
        #pragma unroll
        for (int nn = 0; nn < 16; ++nn) {
            float kr[8], vr[8];
            #pragma unroll
            for (int i = 0; i < 8; ++i) kr[i] = ks[nn][ty * 8 + i];
            #pragma unroll
            for (int j = 0; j < 8; ++j) vr[j] = vs[nn][tx * 8 + j];
            #pragma unroll
            for (int i = 0; i < 8; ++i)
                #pragma unroll
                for (int j = 0; j < 8; ++j)
                    acc[i][j] = fmaf(kr[i], vr[j], acc[i][j]);
        }
        __syncthreads();
    }
    for (int i = 0; i < 8; ++i)
        for (int j = 0; j < 8; ++j)
            ap[(ty * 8 + i) * 128 + tx * 8 + j] = acc[i][j];
}

__global__ __launch_bounds__(256) void reduce_att(const float* __restrict__ att_part,
                                                  float* __restrict__ att) {
    long idx = (long)blockIdx.x * 256 + threadIdx.x;
    if (idx >= (long)64 * 16384) return;
    float s = 0.f;
    #pragma unroll
    for (int sp = 0; sp < ATT_SPLIT; ++sp) s += att_part[(long)sp * 64 * 16384 + idx];
    att[idx] = s;
}

// y[b,t,h*128+l] = sum_d q[b,t,h*128+d] * att[bh][d][l]
__global__ __launch_bounds__(256) void y_kernel(const bf16* __restrict__ q,
                                                const float* __restrict__ att,
                                                bf16* __restrict__ y) {
    int bh = blockIdx.y;
    int b = bh >> 3, h = bh & 7;
    const bf16* qb = q + (long)b * Tc * Dc + h * 128;
    const float* ab = att + (long)bh * 16384;
    bf16* yb = y + (long)b * Tc * Dc + h * 128;
    int t0 = blockIdx.x * 64;
    __shared__ float qs[16][68];
    __shared__ float as[16][128];
    int tid = threadIdx.x, tx = tid & 15, ty = tid >> 4;
    float acc[4][8] = {};
    for (int k0 = 0; k0 < 128; k0 += 16) {
        for (int e = tid; e < 1024; e += 256) {
            int m = e >> 4, k = e & 15;
            qs[k][m] = b2f(qb[(long)(t0 + m) * Dc + k0 + k]);
        }
        for (int e = tid; e < 2048; e += 256) {
            int k = e >> 7, n = e & 127;
            as[k][n] = ab[(k0 + k) * 128 + n];
        }
        __syncthreads();
        #pragma unroll
        for (int k = 0; k < 16; ++k) {
            float a[4], w[8];
            #pragma unroll
            for (int i = 0; i < 4; ++i) a[i] = qs[k][ty * 4 + i];
            #pragma unroll
            for (int j = 0; j < 8; ++j) w[j] = as[k][tx * 8 + j];
            #pragma unroll
            for (int i = 0; i < 4; ++i)
                #pragma unroll
                for (int j = 0; j < 8; ++j)
                    acc[i][j] = fmaf(a[i], w[j], acc[i][j]);
        }
        __syncthreads();
    }
    for (int i = 0; i < 4; ++i)
        for (int j = 0; j < 8; ++j)
            yb[(long)(t0 + ty * 4 + i) * Dc + tx * 8 + j] = f2b(acc[i][j]);
}

// s = silu( LN(y)*(1+scale) + shift )
__global__ __launch_bounds__(256) void film_kernel(const bf16* __restrict__ y,
                                                   const float* __restrict__ eo,
                                                   const float* __restrict__ g,
                                                   const float* __restrict__ bta,
                                                   bf16* __restrict__ s) {
    long row = blockIdx.x;
    int b = (int)(row >> 10);
    const bf16* yr = y + row * Dc;
    float sum = 0.f, sum2 = 0.f;
    for (int c = threadIdx.x; c < Dc; c += 256) { float v = b2f(yr[c]); sum += v; sum2 += v * v; }
    float2 r = block_sum2(sum, sum2);
    float mean = r.x / Dc;
    float var = r.y / Dc - mean * mean;
    float inv = rsqrtf(var + 1e-5f);
    const float* sc = eo + (long)b * 2048;
    const float* sf = sc + 1024;
    bf16* so = s + row * Dc;
    for (int c = threadIdx.x; c < Dc; c += 256) {
        float v = (b2f(yr[c]) - mean) * inv * g[c] + bta[c];
        v = v * (1.f + sc[c]) + sf[c];
        so[c] = f2b(v / (1.f + expf(-v)));
    }
}

extern "C" void kernel_launch(void* const* d_in, const int* in_sizes, int n_in,
                              void* d_out, int out_size, void* d_ws, size_t ws_size,
                              hipStream_t stream) {
    if (ws_size < WS_NEED) return;

    const float* x         = (const float*)d_in[0];
    const float* xf        = (const float*)d_in[1];
    const float* emb       = (const float*)d_in[2];
    const float* src_mask  = (const float*)d_in[3];
    const int*   cond_type = (const int*)d_in[4];
    const float* re_motion = (const float*)d_in[5];
    const float* re_text   = (const float*)d_in[6];
    const float* re_mask   = (const float*)d_in[7];
    const float* ln_g  = (const float*)d_in[8];
    const float* ln_b  = (const float*)d_in[9];
    const float* tln_g = (const float*)d_in[10];
    const float* tln_b = (const float*)d_in[11];
    const float* rn1_g = (const float*)d_in[12];
    const float* rn1_b = (const float*)d_in[13];
    const float* rn2_g = (const float*)d_in[14];
    const float* rn2_b = (const float*)d_in[15];
    const float* Wq  = (const float*)d_in[16];
    const float* bq  = (const float*)d_in[17];
    const float* Wkt = (const float*)d_in[18];
    const float* bkt = (const float*)d_in[19];
    const float* Wvt = (const float*)d_in[20];
    const float* bvt = (const float*)d_in[21];
    const float* Wkm = (const float*)d_in[22];
    const float* bkm = (const float*)d_in[23];
    const float* Wvm = (const float*)d_in[24];
    const float* bvm = (const float*)d_in[25];
    const float* Wkr = (const float*)d_in[26];
    const float* bkr = (const float*)d_in[27];
    const float* Wvr = (const float*)d_in[28];
    const float* bvr = (const float*)d_in[29];
    const float* We  = (const float*)d_in[30];
    const float* be  = (const float*)d_in[31];
    const float* sln_g = (const float*)d_in[32];
    const float* sln_b = (const float*)d_in[33];
    const float* Wo  = (const float*)d_in[34];
    const float* bo  = (const float*)d_in[35];

    float* ws = (float*)d_ws;
    float* stats1   = ws + F_STATS1;
    float* stats2   = ws + F_STATS2;
    float* key_add  = ws + F_KEYADD;
    float* val_mul  = ws + F_VALMUL;
    float* eo       = ws + F_EO;
    float* att      = ws + F_ATT;
    bf16* wb = (bf16*)(ws + F_END);
    bf16* norm_x16 = wb + B_NORMX;
    bf16* q16      = wb + B_Q;
    bf16* key16    = wb + B_KEY;
    bf16* v16      = wb + B_V;
    bf16* nxf16    = wb + B_NXF;
    short* WtQ  = (short*)(wb + B_WQ);
    short* WtKT = (short*)(wb + B_WKT);
    short* WtVT = (short*)(wb + B_WVT);
    short* WtKM = (short*)(wb + B_WKM);
    short* WtVM = (short*)(wb + B_WVM);
    short* WtKR = (short*)(wb + B_WKR);
    short* WtVR = (short*)(wb + B_WVR);
    short* WtO  = (short*)(wb + B_WO);
    float* att_part = (float*)(wb + B_NORMX);  // overlays norm_x16 (dead by then)
    bf16* y16 = wb + B_NORMX;                  // written after att_part consumed
    bf16* s16 = q16;                           // q dead after y_kernel
    float* eo_part = (float*)(wb + B_V);       // overlays v16 (dead after att_kernel)

    float* out = (float*)d_out;
    const long sKey = (long)Nc * Dc;

    // 1. LayerNorms + stats
    ln_rows<bf16><<<dim3(Bc * Tc), dim3(256), 0, stream>>>(x, ln_g, ln_b, norm_x16, Dc);
    ln_rows<bf16><<<dim3(Bc * NTc), dim3(256), 0, stream>>>(xf, tln_g, tln_b, nxf16, LTc);
    ln_stats_both<<<dim3(Bc * KRc), dim3(256), 0, stream>>>(re_motion, re_text, stats1, stats2);

    // 2. Masks
    prep_masks<<<dim3((Bc * Nc + 255) / 256), dim3(256), 0, stream>>>(
        cond_type, src_mask, re_mask, key_add, val_mul);

    // 3. Weight transposes (fp32 [K][N] -> bf16 [N][K])
    transpose_w<<<dim3(32, 32), dim3(256), 0, stream>>>(Wq, WtQ, 1024, 1024);
    transpose_w<<<dim3(32, 24), dim3(256), 0, stream>>>(Wkt, WtKT, 768, 1024);
    transpose_w<<<dim3(32, 24), dim3(256), 0, stream>>>(Wvt, WtVT, 768, 1024);
    transpose_w<<<dim3(32, 32), dim3(256), 0, stream>>>(Wkm, WtKM, 1024, 1024);
    transpose_w<<<dim3(32, 32), dim3(256), 0, stream>>>(Wvm, WtVM, 1024, 1024);
    transpose_w<<<dim3(32, 64), dim3(256), 0, stream>>>(Wkr, WtKR, 2048, 1024);
    transpose_w<<<dim3(32, 32), dim3(256), 0, stream>>>(Wvr, WtVR, 1024, 1024);
    transpose_w<<<dim3(32, 32), dim3(256), 0, stream>>>(Wo, WtO, 1024, 1024);

    // 4. MFMA GEMMs
    gemm_bt<bf16><<<dim3(8, 64, 1), dim3(256), 0, stream>>>(
        (const short*)norm_x16, Dc, 0, WtQ, 1024, bq, nullptr, 0, nullptr, 0,
        nullptr, 0, 0, q16, Dc, 0, Bc * Tc, 1024);
    gemm_bt<bf16><<<dim3(8, 1, Bc), dim3(256), 0, stream>>>(
        (const short*)nxf16, LTc, (long)NTc * LTc, WtKT, 768, bkt,
        key_add + 0, Nc, nullptr, 0, nullptr, 0, 0,
        key16 + 0, Dc, sKey, NTc, 768);
    gemm_lnA_mfma<bf16><<<dim3(8, 8, Bc), dim3(256), 0, stream>>>(
        re_motion, re_text, stats1, rn1_g, rn1_b, WtKR, 2048, bkr,
        key_add + NTc, Nc, nullptr, 0, key16 + (long)NTc * Dc, Dc, sKey, 2048);
    gemm_bt<bf16><<<dim3(8, 8, Bc), dim3(256), 0, stream>>>(
        (const short*)norm_x16, Dc, (long)Tc * Dc, WtKM, 1024, bkm,
        key_add + NTc + KRc, Nc, nullptr, 0, nullptr, 0, 0,
        key16 + (long)(NTc + KRc) * Dc, Dc, sKey, Tc, 1024);
    gemm_bt<bf16><<<dim3(8, 1, Bc), dim3(256), 0, stream>>>(
        (const short*)nxf16, LTc, (long)NTc * LTc, WtVT, 768, bvt,
        nullptr, 0, val_mul + 0, Nc, nullptr, 0, 0,
        v16 + 0, Dc, sKey, NTc, 768);
    gemm_lnA_mfma<bf16><<<dim3(8, 8, Bc), dim3(256), 0, stream>>>(
        re_motion, nullptr, stats2, rn2_g, rn2_b, WtVR, 1024, bvr,
        nullptr, 0, val_mul + NTc, Nc, v16 + (long)NTc * Dc, Dc, sKey, 1024);
    gemm_bt<bf16><<<dim3(8, 8, Bc), dim3(256), 0, stream>>>(
        (const short*)norm_x16, Dc, (long)Tc * Dc, WtVM, 1024, bvm,
        nullptr, 0, val_mul + NTc + KRc, Nc, nullptr, 0, 0,
        v16 + (long)(NTc + KRc) * Dc, Dc, sKey, Tc, 1024);

    // 5. Softmaxes
    softmax_head<<<dim3(Bc * Tc * Hc / 4), dim3(256), 0, stream>>>(q16);
    softmax_tokens<<<dim3(Dc / 64, Bc), dim3(256), 0, stream>>>(key16);

    // 6. att = k^T v (split over N, then reduce)
    att_kernel<<<dim3(Bc * Hc, ATT_SPLIT), dim3(256), 0, stream>>>(key16, v16, att_part);
    reduce_att<<<dim3((64 * 16384 + 255) / 256), dim3(256), 0, stream>>>(att_part, att);

    // 7. y = q @ att
    y_kernel<<<dim3(Tc / 64, Bc * Hc), dim3(256), 0, stream>>>(q16, att, y16);

    // 8. eo = silu(emb) @ We + be  (split-K, 256 blocks; partials overlay v16)
    eo_partial<<<dim3(8, 32), dim3(256), 0, stream>>>(emb, We, eo_part);
    eo_reduce<<<dim3(64), dim3(256), 0, stream>>>(eo_part, be, eo);

    // 9. FiLM + silu
    film_kernel<<<dim3(Bc * Tc), dim3(256), 0, stream>>>(y16, eo, sln_g, sln_b, s16);

    // 10. out = x + s @ Wo + bo
    gemm_bt<float><<<dim3(8, 64, 1), dim3(256), 0, stream>>>(
        (const short*)s16, Dc, 0, WtO, 1024, bo, nullptr, 0, nullptr, 0,
        x, Dc, 0, out, Dc, 0, Bc * Tc, 1024);
}

// Round 5
// 899.148 us; speedup vs baseline: 3.7699x; 1.3645x over previous
//
#include <hip/hip_runtime.h>
#include <hip/hip_bf16.h>
#include <math.h>

using bf16 = __hip_bfloat16;

typedef short s16x8 __attribute__((ext_vector_type(8)));
typedef float f32x4 __attribute__((ext_vector_type(4)));

// Problem dims (fixed by setup_inputs)
constexpr int Bc = 8, Tc = 1024, Dc = 1024, Hc = 8;
constexpr int NTc = 77, LTc = 768, KRc = 1024, Nc = 2125, Ec = 2048;
constexpr float NEGC = -1000000.0f;

// ---- Workspace layout (identical footprint to passing R4 run) ----
constexpr long F_STATS1 = 0;                    // 16,384
constexpr long F_STATS2 = F_STATS1 + 16384;     // 16,384
constexpr long F_KEYADD = F_STATS2 + 16384;     // 17,000
constexpr long F_VALMUL = F_KEYADD + 17000;     // 17,000
constexpr long F_SILU   = F_VALMUL + 17000;     // 16,384 (reused: cs_m[8192] + cs_inv[8192])
constexpr long F_EO     = F_SILU + 16384;       // 16,384
constexpr long F_ATT    = F_EO + 16384;         // 1,048,576
constexpr long F_END    = F_ATT + 1048576;
// bf16 region
constexpr long B_NORMX = 0;                     // 8,388,608 (reused: att_part fp32, then y16)
constexpr long B_Q     = B_NORMX + 8388608;     // 8,388,608 (reused: s16)
constexpr long B_KEY   = B_Q + 8388608;         // 17,408,000
constexpr long B_V     = B_KEY + 17408000;      // 17,408,000 (reused: eo_part fp32 after att)
constexpr long B_NXF   = B_V + 17408000;        // 473,088
constexpr long B_WQ    = B_NXF + 473088;
constexpr long B_WKT   = B_WQ + 1048576;
constexpr long B_WVT   = B_WKT + 786432;
constexpr long B_WKM   = B_WVT + 786432;
constexpr long B_WVM   = B_WKM + 1048576;
constexpr long B_WKR   = B_WVM + 1048576;       // 2,097,152 (reused: ksm part_m/part_s fp32)
constexpr long B_WVR   = B_WKR + 2097152;
constexpr long B_WO    = B_WVR + 1048576;
constexpr long B_END   = B_WO + 1048576;
constexpr size_t WS_NEED = (size_t)F_END * 4 + (size_t)B_END * 2;

__device__ __forceinline__ float b2f(bf16 v) { return __bfloat162float(v); }
__device__ __forceinline__ bf16 f2b(float v) { return __float2bfloat16(v); }
__device__ __forceinline__ short f2s(float v) {
    bf16 h = __float2bfloat16(v);
    return *reinterpret_cast<short*>(&h);
}
__device__ __forceinline__ float us2f(unsigned short u) {
    bf16 h = *reinterpret_cast<bf16*>(&u);
    return __bfloat162float(h);
}
__device__ __forceinline__ void storef(float* p, float v) { *p = v; }
__device__ __forceinline__ void storef(bf16* p, float v) { *p = __float2bfloat16(v); }

// async global->LDS, 16B per lane. LDS dest must be wave-uniform base + lane*16.
typedef __attribute__((address_space(1))) const unsigned int gu32;
typedef __attribute__((address_space(3))) unsigned int lu32;
__device__ __forceinline__ void gl_lds16(const void* g, void* l) {
    __builtin_amdgcn_global_load_lds((gu32*)g, (lu32*)l, 16, 0, 0);
}

__device__ __forceinline__ float2 block_sum2(float s, float s2) {
    #pragma unroll
    for (int off = 32; off > 0; off >>= 1) {
        s  += __shfl_down(s, off, 64);
        s2 += __shfl_down(s2, off, 64);
    }
    __shared__ float sh[4], sh2[4];
    int w = threadIdx.x >> 6, lane = threadIdx.x & 63;
    if (lane == 0) { sh[w] = s; sh2[w] = s2; }
    __syncthreads();
    s = sh[0] + sh[1] + sh[2] + sh[3];
    s2 = sh2[0] + sh2[1] + sh2[2] + sh2[3];
    return make_float2(s, s2);
}

// Row LayerNorm: one block (256 thr) per row
template <typename TO>
__global__ __launch_bounds__(256) void ln_rows(const float* __restrict__ in,
                                               const float* __restrict__ g,
                                               const float* __restrict__ b,
                                               TO* __restrict__ out, int C) {
    long row = blockIdx.x;
    const float* x = in + row * (long)C;
    TO* o = out + row * (long)C;
    float s = 0.f, s2 = 0.f;
    for (int c = threadIdx.x; c < C; c += 256) { float v = x[c]; s += v; s2 += v * v; }
    float2 r = block_sum2(s, s2);
    float mean = r.x / C;
    float var = r.y / C - mean * mean;
    float inv = rsqrtf(var + 1e-5f);
    for (int c = threadIdx.x; c < C; c += 256)
        storef(&o[c], (x[c] - mean) * inv * g[c] + b[c]);
}

// Both retrieval LN stats in one pass over re_motion
__global__ __launch_bounds__(256) void ln_stats_both(const float* __restrict__ motion,
                                                     const float* __restrict__ text,
                                                     float* __restrict__ stats1,
                                                     float* __restrict__ stats2) {
    long row = blockIdx.x;  // b*1024 + k*512 + r
    const float* m = motion + row * 1024;
    const float* tx = text + (row >> 9) * 1024;
    float s = 0.f, s2 = 0.f;
    for (int c = threadIdx.x; c < 1024; c += 256) { float v = m[c]; s += v; s2 += v * v; }
    float2 rm = block_sum2(s, s2);
    __syncthreads();
    float st = 0.f, st2 = 0.f;
    for (int c = threadIdx.x; c < 1024; c += 256) { float v = tx[c]; st += v; st2 += v * v; }
    float2 rt = block_sum2(st, st2);
    if (threadIdx.x == 0) {
        float mean2 = rm.x / 1024.f;
        float var2 = rm.y / 1024.f - mean2 * mean2;
        stats2[2 * row] = mean2;
        stats2[2 * row + 1] = rsqrtf(var2 + 1e-5f);
        float mean1 = (rm.x + rt.x) / 2048.f;
        float var1 = (rm.y + rt.y) / 2048.f - mean1 * mean1;
        stats1[2 * row] = mean1;
        stats1[2 * row + 1] = rsqrtf(var1 + 1e-5f);
    }
}

// Per-(b, n) key additive mask and value multiplicative mask
__global__ __launch_bounds__(256) void prep_masks(const int* __restrict__ cond_type,
                                                  const float* __restrict__ src_mask,
                                                  const float* __restrict__ re_mask,
                                                  float* __restrict__ key_add,
                                                  float* __restrict__ val_mul) {
    int idx = blockIdx.x * 256 + threadIdx.x;
    if (idx >= Bc * Nc) return;
    int b = idx / Nc, n = idx % Nc;
    int ct = cond_type[b];
    float text_ct = ((ct % 10) > 0) ? 1.f : 0.f;
    float retr_ct = ((ct / 10) > 0) ? 1.f : 0.f;
    float add, mul;
    if (n < NTc) {
        add = (1.f - text_ct) * NEGC; mul = text_ct;
    } else if (n < NTc + KRc) {
        float rm = re_mask[b * KRc + (n - NTc)];
        add = (1.f - retr_ct) * NEGC + (1.f - rm) * NEGC;
        mul = retr_ct * rm;
    } else {
        float sm = src_mask[b * Tc + (n - NTc - KRc)];
        add = (1.f - sm) * NEGC; mul = sm;
    }
    key_add[idx] = add;
    val_mul[idx] = mul;
}

// Transpose + convert weight: W[K][N] fp32 -> Wt[N][K] bf16(short)
__global__ __launch_bounds__(256) void transpose_w(const float* __restrict__ W,
                                                   short* __restrict__ Wt,
                                                   int K, int N) {
    __shared__ float t[32][33];
    int n0 = blockIdx.x * 32, k0 = blockIdx.y * 32;
    int tx = threadIdx.x & 31, ty = threadIdx.x >> 5;
    #pragma unroll
    for (int i = 0; i < 4; ++i)
        t[ty + i * 8][tx] = W[(long)(k0 + ty + i * 8) * N + n0 + tx];
    __syncthreads();
    #pragma unroll
    for (int i = 0; i < 4; ++i)
        Wt[(long)(n0 + ty + i * 8) * K + k0 + tx] = f2s(t[tx][ty + i * 8]);
}

// ======================= MFMA GEMM (B^T layout, async LDS staging) ==========
constexpr int LDK = 64;

template <typename TC>
__global__ __launch_bounds__(256) void gemm_bt(
    const short* __restrict__ A, int lda, long sA,
    const short* __restrict__ Bt, int ldb,
    const float* __restrict__ bias,
    const float* __restrict__ rowadd, int sRA,
    const float* __restrict__ rowmul, int sRM,
    const float* __restrict__ addC, int ldac, long sAC,
    TC* __restrict__ C, int ldc, long sC,
    int M, int K) {
    int bz = blockIdx.z;
    A += (long)bz * sA;
    C += (long)bz * sC;
    if (rowadd) rowadd += (long)bz * sRA;
    if (rowmul) rowmul += (long)bz * sRM;
    if (addC) addC += (long)bz * sAC;

    const int tm = blockIdx.y * 128;
    const int tn = blockIdx.x * 128;

    __shared__ __align__(16) short As[128 * LDK];
    __shared__ __align__(16) short Bs[128 * LDK];

    int tid = threadIdx.x;
    int lane = tid & 63, wid = tid >> 6;
    int wi = wid >> 1, wj = wid & 1;
    int l16 = lane & 15, quad = lane >> 4;

    f32x4 acc[4][4];
    #pragma unroll
    for (int i = 0; i < 4; ++i)
        #pragma unroll
        for (int j = 0; j < 4; ++j)
            acc[i][j] = (f32x4){0.f, 0.f, 0.f, 0.f};

    auto issue = [&](int k0) {
        #pragma unroll
        for (int p = 0; p < 4; ++p) {
            int e = p * 256 + tid;
            int row = e >> 3, c8 = e & 7;
            int gm = tm + row;
            if (gm >= M) gm = M - 1;  // clamp: garbage rows never stored
            gl_lds16(A + (long)gm * lda + k0 + c8 * 8, &As[row * LDK + c8 * 8]);
            gl_lds16(Bt + (long)(tn + row) * ldb + k0 + c8 * 8, &Bs[row * LDK + c8 * 8]);
        }
    };

    issue(0);
    int kt = 0;
    while (true) {
        __syncthreads();
        #pragma unroll
        for (int kk = 0; kk < 2; ++kk) {
            s16x8 af[4], bfr[4];
            #pragma unroll
            for (int i = 0; i < 4; ++i)
                af[i] = *(const s16x8*)&As[(wi * 64 + i * 16 + l16) * LDK + kk * 32 + quad * 8];
            #pragma unroll
            for (int j = 0; j < 4; ++j)
                bfr[j] = *(const s16x8*)&Bs[(wj * 64 + j * 16 + l16) * LDK + kk * 32 + quad * 8];
            #pragma unroll
            for (int i = 0; i < 4; ++i)
                #pragma unroll
                for (int j = 0; j < 4; ++j)
                    acc[i][j] = __builtin_amdgcn_mfma_f32_16x16x32_bf16(af[i], bfr[j], acc[i][j], 0, 0, 0);
        }
        int nxt = kt + 64;
        if (nxt >= K) break;
        __syncthreads();
        issue(nxt);
        kt = nxt;
    }

    #pragma unroll
    for (int i = 0; i < 4; ++i) {
        #pragma unroll
        for (int r = 0; r < 4; ++r) {
            int gm = tm + wi * 64 + i * 16 + quad * 4 + r;
            if (gm >= M) continue;
            float ra = rowadd ? rowadd[gm] : 0.f;
            float rm = rowmul ? rowmul[gm] : 1.f;
            #pragma unroll
            for (int j = 0; j < 4; ++j) {
                int gn = tn + wj * 64 + j * 16 + l16;
                float v = acc[i][j][r] + (bias ? bias[gn] : 0.f) + ra;
                v *= rm;
                if (addC) v += addC[(long)gm * ldac + gn];
                storef(&C[(long)gm * ldc + gn], v);
            }
        }
    }
}

// MFMA GEMM with LayerNorm fused into A staging (A via regs->LDS, B async).
template <typename TC>
__global__ __launch_bounds__(256) void gemm_lnA_mfma(
    const float* __restrict__ motion, const float* __restrict__ text,
    const float* __restrict__ stats,
    const float* __restrict__ g, const float* __restrict__ bvec,
    const short* __restrict__ Bt, int ldb,
    const float* __restrict__ bias,
    const float* __restrict__ rowadd, int sRA,
    const float* __restrict__ rowmul, int sRM,
    TC* __restrict__ C, int ldc, long sC,
    int K) {
    int bz = blockIdx.z;
    C += (long)bz * sC;
    if (rowadd) rowadd += (long)bz * sRA;
    if (rowmul) rowmul += (long)bz * sRM;

    const int tm = blockIdx.y * 128;
    const int tn = blockIdx.x * 128;

    __shared__ __align__(16) short As[128 * LDK];
    __shared__ __align__(16) short Bs[128 * LDK];

    int tid = threadIdx.x;
    int lane = tid & 63, wid = tid >> 6;
    int wi = wid >> 1, wj = wid & 1;
    int l16 = lane & 15, quad = lane >> 4;

    f32x4 acc[4][4];
    #pragma unroll
    for (int i = 0; i < 4; ++i)
        #pragma unroll
        for (int j = 0; j < 4; ++j)
            acc[i][j] = (f32x4){0.f, 0.f, 0.f, 0.f};

    uint4 pa[4];

    auto computeA = [&](int k0) {
        #pragma unroll
        for (int p = 0; p < 4; ++p) {
            int e = p * 256 + tid;
            int row = e >> 3, c8 = e & 7;
            long rg = (long)bz * 1024 + tm + row;
            int c = k0 + c8 * 8;
            const float* src = (c < 1024) ? motion + rg * 1024 + c
                                          : text + (rg >> 9) * 1024 + (c - 1024);
            float4 v0 = *(const float4*)src;
            float4 v1 = *(const float4*)(src + 4);
            float mean = stats[2 * rg], rstd = stats[2 * rg + 1];
            float4 g0 = *(const float4*)&g[c], g1 = *(const float4*)&g[c + 4];
            float4 b0 = *(const float4*)&bvec[c], b1 = *(const float4*)&bvec[c + 4];
            union { short s[8]; uint4 u; } pk;
            pk.s[0] = f2s((v0.x - mean) * rstd * g0.x + b0.x);
            pk.s[1] = f2s((v0.y - mean) * rstd * g0.y + b0.y);
            pk.s[2] = f2s((v0.z - mean) * rstd * g0.z + b0.z);
            pk.s[3] = f2s((v0.w - mean) * rstd * g0.w + b0.w);
            pk.s[4] = f2s((v1.x - mean) * rstd * g1.x + b1.x);
            pk.s[5] = f2s((v1.y - mean) * rstd * g1.y + b1.y);
            pk.s[6] = f2s((v1.z - mean) * rstd * g1.z + b1.z);
            pk.s[7] = f2s((v1.w - mean) * rstd * g1.w + b1.w);
            pa[p] = pk.u;
        }
    };
    auto issueB = [&](int k0) {
        #pragma unroll
        for (int p = 0; p < 4; ++p) {
            int e = p * 256 + tid;
            int row = e >> 3, c8 = e & 7;
            gl_lds16(Bt + (long)(tn + row) * ldb + k0 + c8 * 8, &Bs[row * LDK + c8 * 8]);
        }
    };
    auto storeA = [&]() {
        #pragma unroll
        for (int p = 0; p < 4; ++p) {
            int e = p * 256 + tid;
            int row = e >> 3, c8 = e & 7;
            *(uint4*)&As[row * LDK + c8 * 8] = pa[p];
        }
    };

    issueB(0);
    computeA(0);
    storeA();
    int kt = 0;
    while (true) {
        __syncthreads();
        #pragma unroll
        for (int kk = 0; kk < 2; ++kk) {
            s16x8 af[4], bfr[4];
            #pragma unroll
            for (int i = 0; i < 4; ++i)
                af[i] = *(const s16x8*)&As[(wi * 64 + i * 16 + l16) * LDK + kk * 32 + quad * 8];
            #pragma unroll
            for (int j = 0; j < 4; ++j)
                bfr[j] = *(const s16x8*)&Bs[(wj * 64 + j * 16 + l16) * LDK + kk * 32 + quad * 8];
            #pragma unroll
            for (int i = 0; i < 4; ++i)
                #pragma unroll
                for (int j = 0; j < 4; ++j)
                    acc[i][j] = __builtin_amdgcn_mfma_f32_16x16x32_bf16(af[i], bfr[j], acc[i][j], 0, 0, 0);
        }
        int nxt = kt + 64;
        if (nxt >= K) break;
        computeA(nxt);
        __syncthreads();
        issueB(nxt);
        storeA();
        kt = nxt;
    }

    #pragma unroll
    for (int i = 0; i < 4; ++i) {
        #pragma unroll
        for (int r = 0; r < 4; ++r) {
            int gm = tm + wi * 64 + i * 16 + quad * 4 + r;
            float ra = rowadd ? rowadd[gm] : 0.f;
            float rm = rowmul ? rowmul[gm] : 1.f;
            #pragma unroll
            for (int j = 0; j < 4; ++j) {
                int gn = tn + wj * 64 + j * 16 + l16;
                float v = acc[i][j][r] + (bias ? bias[gn] : 0.f) + ra;
                v *= rm;
                storef(&C[(long)gm * ldc + gn], v);
            }
        }
    }
}

// eo split-K
__global__ __launch_bounds__(256) void eo_partial(const float* __restrict__ emb,
                                                  const float* __restrict__ We,
                                                  float* __restrict__ part) {
    int nb = blockIdx.x;
    int ks = blockIdx.y;
    int n = nb * 256 + threadIdx.x;
    int k0 = ks * 64;
    __shared__ float a_s[8][64];
    for (int idx = threadIdx.x; idx < 512; idx += 256) {
        int b = idx >> 6, kk = idx & 63;
        float v = emb[b * 2048 + k0 + kk];
        a_s[b][kk] = v / (1.f + expf(-v));
    }
    __syncthreads();
    float acc[8] = {};
    for (int kk = 0; kk < 64; ++kk) {
        float w = We[(long)(k0 + kk) * 2048 + n];
        #pragma unroll
        for (int b = 0; b < 8; ++b) acc[b] = fmaf(a_s[b][kk], w, acc[b]);
    }
    #pragma unroll
    for (int b = 0; b < 8; ++b) part[((long)ks * 8 + b) * 2048 + n] = acc[b];
}

__global__ __launch_bounds__(256) void eo_reduce(const float* __restrict__ part,
                                                 const float* __restrict__ be,
                                                 float* __restrict__ eo) {
    int idx = blockIdx.x * 256 + threadIdx.x;
    int n = idx & 2047, b = idx >> 11;
    float s = be[n];
    #pragma unroll 8
    for (int ks = 0; ks < 32; ++ks) s += part[((long)ks * 8 + b) * 2048 + n];
    eo[idx] = s;
}

// q softmax over head dim (128): one wave per row, 2 elems/lane.
__global__ __launch_bounds__(256) void softmax_head(bf16* __restrict__ q) {
    long row = (long)blockIdx.x * 4 + (threadIdx.x >> 6);
    int lane = threadIdx.x & 63;
    bf16* p = q + row * 128 + lane * 2;
    float v0 = b2f(p[0]), v1 = b2f(p[1]);
    float mx = fmaxf(v0, v1);
    #pragma unroll
    for (int off = 32; off > 0; off >>= 1) mx = fmaxf(mx, __shfl_xor(mx, off, 64));
    float e0 = expf(v0 - mx), e1 = expf(v1 - mx);
    float s = e0 + e1;
    #pragma unroll
    for (int off = 32; off > 0; off >>= 1) s += __shfl_xor(s, off, 64);
    float inv = 1.f / s;
    p[0] = f2b(e0 * inv);
    p[1] = f2b(e1 * inv);
}

// ===== key-softmax over tokens, pass 1: per-(split,b) online (max,sumexp) per column
constexpr int KSM_NS = 32;
__global__ __launch_bounds__(256) void ksm_partial(const bf16* __restrict__ key,
                                                   float* __restrict__ part_m,
                                                   float* __restrict__ part_s) {
    int split = blockIdx.x, b = blockIdx.y;
    const int per = (Nc + KSM_NS - 1) / KSM_NS;  // 67
    int n0 = split * per, n1 = min(Nc, n0 + per);
    int c4 = threadIdx.x * 4;
    const unsigned short* kp = (const unsigned short*)(key + (long)b * Nc * Dc) + c4;
    float m[4] = {-3.0e38f, -3.0e38f, -3.0e38f, -3.0e38f};
    float s[4] = {0.f, 0.f, 0.f, 0.f};
    for (int n = n0; n < n1; ++n) {
        ushort4 raw = *(const ushort4*)(kp + (long)n * Dc);
        unsigned short rr[4] = {raw.x, raw.y, raw.z, raw.w};
        #pragma unroll
        for (int j = 0; j < 4; ++j) {
            float v = us2f(rr[j]);
            if (v <= m[j]) {
                s[j] += __expf(v - m[j]);
            } else {
                s[j] = s[j] * __expf(m[j] - v) + 1.f;
                m[j] = v;
            }
        }
    }
    long off = ((long)split * Bc + b) * Dc + c4;
    #pragma unroll
    for (int j = 0; j < 4; ++j) { part_m[off + j] = m[j]; part_s[off + j] = s[j]; }
}

// pass 2: combine split partials -> per-column (max, 1/sum)
__global__ __launch_bounds__(256) void ksm_reduce(const float* __restrict__ part_m,
                                                  const float* __restrict__ part_s,
                                                  float* __restrict__ cs_m,
                                                  float* __restrict__ cs_inv) {
    int idx = blockIdx.x * 256 + threadIdx.x;  // b*1024 + c, 8192 total
    float gm = -3.0e38f;
    #pragma unroll 8
    for (int sp = 0; sp < KSM_NS; ++sp)
        gm = fmaxf(gm, part_m[(long)sp * Bc * Dc + idx]);
    float s = 0.f;
    #pragma unroll 8
    for (int sp = 0; sp < KSM_NS; ++sp)
        s += part_s[(long)sp * Bc * Dc + idx] * __expf(part_m[(long)sp * Bc * Dc + idx] - gm);
    cs_m[idx] = gm;
    cs_inv[idx] = 1.f / s;
}

// att_part[split][bh][d][l] = sum_{n in split} exp(k[b,n,h*128+d]-m_d) * v[b,n,h*128+l]
constexpr int ATT_SPLIT = 4;
__global__ __launch_bounds__(256) void att_kernel(const bf16* __restrict__ key,
                                                  const bf16* __restrict__ v,
                                                  const float* __restrict__ cs_m,
                                                  float* __restrict__ att_part) {
    int bh = blockIdx.x;
    int b = bh >> 3, h = bh & 7;
    int split = blockIdx.y;
    const bf16* kb = key + (long)b * Nc * Dc + h * 128;
    const bf16* vb = v + (long)b * Nc * Dc + h * 128;
    float* ap = att_part + ((long)split * 64 + bh) * 16384;
    const int per = (Nc + ATT_SPLIT - 1) / ATT_SPLIT;  // 532
    int n0 = split * per, n1 = min(Nc, n0 + per);
    __shared__ float ks[16][128], vs[16][128];
    __shared__ float ms[128];
    int tid = threadIdx.x, tx = tid & 15, ty = tid >> 4;
    if (tid < 128) ms[tid] = cs_m[b * Dc + h * 128 + tid];
    __syncthreads();
    float acc[8][8] = {};
    for (int nb = n0; nb < n1; nb += 16) {
        int nc = min(16, n1 - nb);
        for (int e = tid; e < 2048; e += 256) {
            int nn = e >> 7, d = e & 127;
            float kvv = 0.f, vvv = 0.f;
            if (nn < nc) {
                long off = (long)(nb + nn) * Dc + d;
                kvv = __expf(b2f(kb[off]) - ms[d]);
                vvv = b2f(vb[off]);
            }
            ks[nn][d] = kvv; vs[nn][d] = vvv;
        }
        __syncthreads();
        #pragma unroll
        for (int nn = 0; nn < 16; ++nn) {
            float kr[8], vr[8];
            #pragma unroll
            for (int i = 0; i < 8; ++i) kr[i] = ks[nn][ty * 8 + i];
            #pragma unroll
            for (int j = 0; j < 8; ++j) vr[j] = vs[nn][tx * 8 + j];
            #pragma unroll
            for (int i = 0; i < 8; ++i)
                #pragma unroll
                for (int j = 0; j < 8; ++j)
                    acc[i][j] = fmaf(kr[i], vr[j], acc[i][j]);
        }
        __syncthreads();
    }
    for (int i = 0; i < 8; ++i)
        for (int j = 0; j < 8; ++j)
            ap[(ty * 8 + i) * 128 + tx * 8 + j] = acc[i][j];
}

// reduce + apply per-d 1/sum
__global__ __launch_bounds__(256) void reduce_att(const float* __restrict__ att_part,
                                                  const float* __restrict__ cs_inv,
                                                  float* __restrict__ att) {
    long idx = (long)blockIdx.x * 256 + threadIdx.x;
    if (idx >= (long)64 * 16384) return;
    float s = 0.f;
    #pragma unroll
    for (int sp = 0; sp < ATT_SPLIT; ++sp) s += att_part[(long)sp * 64 * 16384 + idx];
    int bh = (int)(idx >> 14);
    int d = (int)((idx >> 7) & 127);
    int b = bh >> 3, h = bh & 7;
    att[idx] = s * cs_inv[b * Dc + h * 128 + d];
}

// y[b,t,h*128+l] = sum_d q[b,t,h*128+d] * att[bh][d][l]
__global__ __launch_bounds__(256) void y_kernel(const bf16* __restrict__ q,
                                                const float* __restrict__ att,
                                                bf16* __restrict__ y) {
    int bh = blockIdx.y;
    int b = bh >> 3, h = bh & 7;
    const bf16* qb = q + (long)b * Tc * Dc + h * 128;
    const float* ab = att + (long)bh * 16384;
    bf16* yb = y + (long)b * Tc * Dc + h * 128;
    int t0 = blockIdx.x * 64;
    __shared__ float qs[16][68];
    __shared__ float as[16][128];
    int tid = threadIdx.x, tx = tid & 15, ty = tid >> 4;
    float acc[4][8] = {};
    for (int k0 = 0; k0 < 128; k0 += 16) {
        for (int e = tid; e < 1024; e += 256) {
            int m = e >> 4, k = e & 15;
            qs[k][m] = b2f(qb[(long)(t0 + m) * Dc + k0 + k]);
        }
        for (int e = tid; e < 2048; e += 256) {
            int k = e >> 7, n = e & 127;
            as[k][n] = ab[(k0 + k) * 128 + n];
        }
        __syncthreads();
        #pragma unroll
        for (int k = 0; k < 16; ++k) {
            float a[4], w[8];
            #pragma unroll
            for (int i = 0; i < 4; ++i) a[i] = qs[k][ty * 4 + i];
            #pragma unroll
            for (int j = 0; j < 8; ++j) w[j] = as[k][tx * 8 + j];
            #pragma unroll
            for (int i = 0; i < 4; ++i)
                #pragma unroll
                for (int j = 0; j < 8; ++j)
                    acc[i][j] = fmaf(a[i], w[j], acc[i][j]);
        }
        __syncthreads();
    }
    for (int i = 0; i < 4; ++i)
        for (int j = 0; j < 8; ++j)
            yb[(long)(t0 + ty * 4 + i) * Dc + tx * 8 + j] = f2b(acc[i][j]);
}

// s = silu( LN(y)*(1+scale) + shift )
__global__ __launch_bounds__(256) void film_kernel(const bf16* __restrict__ y,
                                                   const float* __restrict__ eo,
                                                   const float* __restrict__ g,
                                                   const float* __restrict__ bta,
                                                   bf16* __restrict__ s) {
    long row = blockIdx.x;
    int b = (int)(row >> 10);
    const bf16* yr = y + row * Dc;
    float sum = 0.f, sum2 = 0.f;
    for (int c = threadIdx.x; c < Dc; c += 256) { float v = b2f(yr[c]); sum += v; sum2 += v * v; }
    float2 r = block_sum2(sum, sum2);
    float mean = r.x / Dc;
    float var = r.y / Dc - mean * mean;
    float inv = rsqrtf(var + 1e-5f);
    const float* sc = eo + (long)b * 2048;
    const float* sf = sc + 1024;
    bf16* so = s + row * Dc;
    for (int c = threadIdx.x; c < Dc; c += 256) {
        float v = (b2f(yr[c]) - mean) * inv * g[c] + bta[c];
        v = v * (1.f + sc[c]) + sf[c];
        so[c] = f2b(v / (1.f + expf(-v)));
    }
}

extern "C" void kernel_launch(void* const* d_in, const int* in_sizes, int n_in,
                              void* d_out, int out_size, void* d_ws, size_t ws_size,
                              hipStream_t stream) {
    if (ws_size < WS_NEED) return;

    const float* x         = (const float*)d_in[0];
    const float* xf        = (const float*)d_in[1];
    const float* emb       = (const float*)d_in[2];
    const float* src_mask  = (const float*)d_in[3];
    const int*   cond_type = (const int*)d_in[4];
    const float* re_motion = (const float*)d_in[5];
    const float* re_text   = (const float*)d_in[6];
    const float* re_mask   = (const float*)d_in[7];
    const float* ln_g  = (const float*)d_in[8];
    const float* ln_b  = (const float*)d_in[9];
    const float* tln_g = (const float*)d_in[10];
    const float* tln_b = (const float*)d_in[11];
    const float* rn1_g = (const float*)d_in[12];
    const float* rn1_b = (const float*)d_in[13];
    const float* rn2_g = (const float*)d_in[14];
    const float* rn2_b = (const float*)d_in[15];
    const float* Wq  = (const float*)d_in[16];
    const float* bq  = (const float*)d_in[17];
    const float* Wkt = (const float*)d_in[18];
    const float* bkt = (const float*)d_in[19];
    const float* Wvt = (const float*)d_in[20];
    const float* bvt = (const float*)d_in[21];
    const float* Wkm = (const float*)d_in[22];
    const float* bkm = (const float*)d_in[23];
    const float* Wvm = (const float*)d_in[24];
    const float* bvm = (const float*)d_in[25];
    const float* Wkr = (const float*)d_in[26];
    const float* bkr = (const float*)d_in[27];
    const float* Wvr = (const float*)d_in[28];
    const float* bvr = (const float*)d_in[29];
    const float* We  = (const float*)d_in[30];
    const float* be  = (const float*)d_in[31];
    const float* sln_g = (const float*)d_in[32];
    const float* sln_b = (const float*)d_in[33];
    const float* Wo  = (const float*)d_in[34];
    const float* bo  = (const float*)d_in[35];

    float* ws = (float*)d_ws;
    float* stats1   = ws + F_STATS1;
    float* stats2   = ws + F_STATS2;
    float* key_add  = ws + F_KEYADD;
    float* val_mul  = ws + F_VALMUL;
    float* cs_m     = ws + F_SILU;         // 8192
    float* cs_inv   = cs_m + Bc * Dc;      // 8192
    float* eo       = ws + F_EO;
    float* att      = ws + F_ATT;
    bf16* wb = (bf16*)(ws + F_END);
    bf16* norm_x16 = wb + B_NORMX;
    bf16* q16      = wb + B_Q;
    bf16* key16    = wb + B_KEY;
    bf16* v16      = wb + B_V;
    bf16* nxf16    = wb + B_NXF;
    short* WtQ  = (short*)(wb + B_WQ);
    short* WtKT = (short*)(wb + B_WKT);
    short* WtVT = (short*)(wb + B_WVT);
    short* WtKM = (short*)(wb + B_WKM);
    short* WtVM = (short*)(wb + B_WVM);
    short* WtKR = (short*)(wb + B_WKR);
    short* WtVR = (short*)(wb + B_WVR);
    short* WtO  = (short*)(wb + B_WO);
    float* att_part = (float*)(wb + B_NORMX);  // overlays norm_x16 (dead by then)
    bf16* y16 = wb + B_NORMX;                  // written after att_part consumed
    bf16* s16 = q16;                           // q dead after y_kernel
    float* eo_part = (float*)(wb + B_V);       // overlays v16 (dead after att_kernel)
    float* part_m = (float*)(wb + B_WKR);      // overlays WtKR (dead after key_retr gemm)
    float* part_s = part_m + (long)KSM_NS * Bc * Dc;  // 262,144 + 262,144 < 1,048,576 floats

    float* out = (float*)d_out;
    const long sKey = (long)Nc * Dc;

    // 1. LayerNorms + stats
    ln_rows<bf16><<<dim3(Bc * Tc), dim3(256), 0, stream>>>(x, ln_g, ln_b, norm_x16, Dc);
    ln_rows<bf16><<<dim3(Bc * NTc), dim3(256), 0, stream>>>(xf, tln_g, tln_b, nxf16, LTc);
    ln_stats_both<<<dim3(Bc * KRc), dim3(256), 0, stream>>>(re_motion, re_text, stats1, stats2);

    // 2. Masks
    prep_masks<<<dim3((Bc * Nc + 255) / 256), dim3(256), 0, stream>>>(
        cond_type, src_mask, re_mask, key_add, val_mul);

    // 3. Weight transposes
    transpose_w<<<dim3(32, 32), dim3(256), 0, stream>>>(Wq, WtQ, 1024, 1024);
    transpose_w<<<dim3(32, 24), dim3(256), 0, stream>>>(Wkt, WtKT, 768, 1024);
    transpose_w<<<dim3(32, 24), dim3(256), 0, stream>>>(Wvt, WtVT, 768, 1024);
    transpose_w<<<dim3(32, 32), dim3(256), 0, stream>>>(Wkm, WtKM, 1024, 1024);
    transpose_w<<<dim3(32, 32), dim3(256), 0, stream>>>(Wvm, WtVM, 1024, 1024);
    transpose_w<<<dim3(32, 64), dim3(256), 0, stream>>>(Wkr, WtKR, 2048, 1024);
    transpose_w<<<dim3(32, 32), dim3(256), 0, stream>>>(Wvr, WtVR, 1024, 1024);
    transpose_w<<<dim3(32, 32), dim3(256), 0, stream>>>(Wo, WtO, 1024, 1024);

    // 4. MFMA GEMMs
    gemm_bt<bf16><<<dim3(8, 64, 1), dim3(256), 0, stream>>>(
        (const short*)norm_x16, Dc, 0, WtQ, 1024, bq, nullptr, 0, nullptr, 0,
        nullptr, 0, 0, q16, Dc, 0, Bc * Tc, 1024);
    gemm_bt<bf16><<<dim3(8, 1, Bc), dim3(256), 0, stream>>>(
        (const short*)nxf16, LTc, (long)NTc * LTc, WtKT, 768, bkt,
        key_add + 0, Nc, nullptr, 0, nullptr, 0, 0,
        key16 + 0, Dc, sKey, NTc, 768);
    gemm_lnA_mfma<bf16><<<dim3(8, 8, Bc), dim3(256), 0, stream>>>(
        re_motion, re_text, stats1, rn1_g, rn1_b, WtKR, 2048, bkr,
        key_add + NTc, Nc, nullptr, 0, key16 + (long)NTc * Dc, Dc, sKey, 2048);
    gemm_bt<bf16><<<dim3(8, 8, Bc), dim3(256), 0, stream>>>(
        (const short*)norm_x16, Dc, (long)Tc * Dc, WtKM, 1024, bkm,
        key_add + NTc + KRc, Nc, nullptr, 0, nullptr, 0, 0,
        key16 + (long)(NTc + KRc) * Dc, Dc, sKey, Tc, 1024);
    gemm_bt<bf16><<<dim3(8, 1, Bc), dim3(256), 0, stream>>>(
        (const short*)nxf16, LTc, (long)NTc * LTc, WtVT, 768, bvt,
        nullptr, 0, val_mul + 0, Nc, nullptr, 0, 0,
        v16 + 0, Dc, sKey, NTc, 768);
    gemm_lnA_mfma<bf16><<<dim3(8, 8, Bc), dim3(256), 0, stream>>>(
        re_motion, nullptr, stats2, rn2_g, rn2_b, WtVR, 1024, bvr,
        nullptr, 0, val_mul + NTc, Nc, v16 + (long)NTc * Dc, Dc, sKey, 1024);
    gemm_bt<bf16><<<dim3(8, 8, Bc), dim3(256), 0, stream>>>(
        (const short*)norm_x16, Dc, (long)Tc * Dc, WtVM, 1024, bvm,
        nullptr, 0, val_mul + NTc + KRc, Nc, nullptr, 0, 0,
        v16 + (long)(NTc + KRc) * Dc, Dc, sKey, Tc, 1024);

    // 5. Softmaxes: q in place; key via column stats only (no key rewrite)
    softmax_head<<<dim3(Bc * Tc * Hc / 4), dim3(256), 0, stream>>>(q16);
    ksm_partial<<<dim3(KSM_NS, Bc), dim3(256), 0, stream>>>(key16, part_m, part_s);
    ksm_reduce<<<dim3(32), dim3(256), 0, stream>>>(part_m, part_s, cs_m, cs_inv);

    // 6. att = p^T v with exp fused into k-load; inv_d applied in reduce
    att_kernel<<<dim3(Bc * Hc, ATT_SPLIT), dim3(256), 0, stream>>>(key16, v16, cs_m, att_part);
    reduce_att<<<dim3((64 * 16384 + 255) / 256), dim3(256), 0, stream>>>(att_part, cs_inv, att);

    // 7. y = q @ att
    y_kernel<<<dim3(Tc / 64, Bc * Hc), dim3(256), 0, stream>>>(q16, att, y16);

    // 8. eo = silu(emb) @ We + be
    eo_partial<<<dim3(8, 32), dim3(256), 0, stream>>>(emb, We, eo_part);
    eo_reduce<<<dim3(64), dim3(256), 0, stream>>>(eo_part, be, eo);

    // 9. FiLM + silu
    film_kernel<<<dim3(Bc * Tc), dim3(256), 0, stream>>>(y16, eo, sln_g, sln_b, s16);

    // 10. out = x + s @ Wo + bo
    gemm_bt<float><<<dim3(8, 64, 1), dim3(256), 0, stream>>>(
        (const short*)s16, Dc, 0, WtO, 1024, bo, nullptr, 0, nullptr, 0,
        x, Dc, 0, out, Dc, 0, Bc * Tc, 1024);
}